// Round 1
// baseline (13980.093 us; speedup 1.0000x reference)
//
#include <hip/hip_runtime.h>
#include <math.h>

#define NN 100000
#define NE 1200000
#define EMBD 100
#define HD 64
#define BT 4096

__device__ __forceinline__ float4 f4zero() { return make_float4(0.f, 0.f, 0.f, 0.f); }
__device__ __forceinline__ float4 f4fma(float4 acc, float4 w, float s) {
    acc.x = fmaf(w.x, s, acc.x);
    acc.y = fmaf(w.y, s, acc.y);
    acc.z = fmaf(w.z, s, acc.z);
    acc.w = fmaf(w.w, s, acc.w);
    return acc;
}
__device__ __forceinline__ float4 f4axpy(float4 b, float4 x, float s) { // b + s*x
    return make_float4(fmaf(s, x.x, b.x), fmaf(s, x.y, b.y), fmaf(s, x.z, b.z), fmaf(s, x.w, b.w));
}
__device__ __forceinline__ float sig1(float x) { return 1.f / (1.f + __expf(-x)); }
__device__ __forceinline__ float tanh1(float x) {
    x = fminf(fmaxf(x, -15.f), 15.f);
    float e = __expf(2.f * x);
    return (e - 1.f) / (e + 1.f);
}

// ---- precompute Wf[l] = Wm[l] @ Wih[l] (64x192), bf[l] = bm[l] @ Wih[l] (192) ----
__global__ __launch_bounds__(256) void fusew_kernel(
    const float* __restrict__ Wm0, const float* __restrict__ Wih0, const float* __restrict__ bm0,
    const float* __restrict__ Wm1, const float* __restrict__ Wih1, const float* __restrict__ bm1,
    float* __restrict__ Wf, float* __restrict__ bf) {
    extern __shared__ float lds[];
    float* wm_s = lds;          // 4096
    float* wih_s = lds + 4096;  // 12288
    const int l = blockIdx.x >> 3, slice = blockIdx.x & 7;
    const float* Wm = l ? Wm1 : Wm0;
    const float* Wih = l ? Wih1 : Wih0;
    const float* bm = l ? bm1 : bm0;
    for (int i = threadIdx.x; i < 4096; i += 256) wm_s[i] = Wm[i];
    for (int i = threadIdx.x; i < 12288; i += 256) wih_s[i] = Wih[i];
    __syncthreads();
    float* Wfl = Wf + l * 12288;
    float* bfl = bf + l * 192;
    const int o0 = slice * 1536;
    for (int o = o0 + threadIdx.x; o < o0 + 1536; o += 256) {
        int r = o / 192, c = o % 192;
        float s = 0.f;
        for (int k = 0; k < 64; ++k) s = fmaf(wm_s[r * 64 + k], wih_s[k * 192 + c], s);
        Wfl[o] = s;
    }
    const int c0 = slice * 24;
    for (int c = c0 + threadIdx.x; c < c0 + 24; c += 256) {
        float s = 0.f;
        for (int k = 0; k < 64; ++k) s = fmaf(bm[k], wih_s[k * 192 + c], s);
        bfl[c] = s;
    }
}

// ---- h[n] = emb_table[ind[n]] @ Wp + bp ----
__global__ __launch_bounds__(256) void embed_kernel(
    const int* __restrict__ ind, const float* __restrict__ emb,
    const float* __restrict__ Wp, const float* __restrict__ bp, float* __restrict__ h) {
    const int node = blockIdx.x * 4 + (threadIdx.x >> 6);
    const int j = threadIdx.x & 63;
    const int idx = ind[node];
    const float* e = emb + idx * EMBD;
    float acc = bp[j];
#pragma unroll 4
    for (int k = 0; k < EMBD; ++k) acc = fmaf(e[k], Wp[k * 64 + j], acc);
    h[node * 64 + j] = acc;
}

// ---- deg[tgt]++ ----
__global__ __launch_bounds__(256) void deg_kernel(const int* __restrict__ adj, float* __restrict__ deg) {
    const int e = blockIdx.x * 256 + threadIdx.x;
    if (e < NE) atomicAdd(&deg[adj[2 * e + 1]], 1.f);
}

// ---- agg[tgt] += h[src], 16 lanes x float4 per edge ----
__global__ __launch_bounds__(256) void scatter_kernel(
    const int* __restrict__ adj, const float* __restrict__ h, float* __restrict__ agg) {
    const int t = threadIdx.x;
    const int e = blockIdx.x * 16 + (t >> 4);
    const int sub = t & 15;
    const int2 st = ((const int2*)adj)[e];
    const float4 v = ((const float4*)h)[st.x * 16 + sub];
    float* dst = agg + st.y * 64 + sub * 4;
    atomicAdd(dst + 0, v.x);
    atomicAdd(dst + 1, v.y);
    atomicAdd(dst + 2, v.z);
    atomicAdd(dst + 3, v.w);
}

// ---- fused: gi = agg@Wf + deg*bf + bih ; gh = h@Whh + bhh ; GRU elementwise -> h (in place)
// Also zeroes agg rows for the next timestep.
__global__ __launch_bounds__(512) void gru_kernel(
    float* __restrict__ h, float* __restrict__ agg, const float* __restrict__ deg,
    const float* __restrict__ Wf, const float* __restrict__ bf,
    const float* __restrict__ bih, const float* __restrict__ Whh, const float* __restrict__ bhh) {
    extern __shared__ float lds[];
    float* wf_s = lds;           // 12288
    float* wh_s = lds + 12288;   // 12288
    float* a_s = lds + 24576;    // 64*68 = 4352
    float* h_s = lds + 28928;    // 4352
    float* deg_s = lds + 33280;  // 64
    const int t = threadIdx.x;
    const int cq = t & 15;   // col-quad 0..15 (cols cq*4..cq*4+3 within each 64-wide gate)
    const int np = t >> 4;   // node-pair 0..31
    // stage weights once per block
    {
        const float4* wf4 = (const float4*)Wf;
        const float4* wh4 = (const float4*)Whh;
        float4* wfs4 = (float4*)wf_s;
        float4* whs4 = (float4*)wh_s;
        for (int i = t; i < 3072; i += 512) {
            wfs4[i] = wf4[i];
            whs4[i] = wh4[i];
        }
    }
    const float4* bih4 = (const float4*)bih;
    const float4* bf4p = (const float4*)bf;
    const float4* bhh4 = (const float4*)bhh;
    const float4 bihr = bih4[cq], bihz = bih4[16 + cq], bihg = bih4[32 + cq];
    const float4 bfr = bf4p[cq], bfz = bf4p[16 + cq], bfg = bf4p[32 + cq];
    const float4 bhr = bhh4[cq], bhz = bhh4[16 + cq], bhg = bhh4[32 + cq];
    const int n0 = 2 * np, n1 = 2 * np + 1;

    for (int tile = blockIdx.x; tile * 64 < NN; tile += gridDim.x) {
        const int base = tile * 64;
        __syncthreads();  // protect LDS tiles from previous iteration's readers
        {
            float4* agg4 = (float4*)agg;
            const float4* h4 = (const float4*)h;
            for (int i = t; i < 1024; i += 512) {
                const int r = i >> 4, c = i & 15;
                const int node = base + r;
                float4 va = f4zero(), vh = f4zero();
                if (node < NN) {
                    va = agg4[node * 16 + c];
                    vh = h4[node * 16 + c];
                    agg4[node * 16 + c] = f4zero();  // ready for next scatter
                }
                *(float4*)(a_s + r * 68 + c * 4) = va;
                *(float4*)(h_s + r * 68 + c * 4) = vh;
            }
            if (t < 64) deg_s[t] = (base + t < NN) ? deg[base + t] : 0.f;
        }
        __syncthreads();
        const float d0 = deg_s[n0], d1 = deg_s[n1];
        float4 gir0 = f4axpy(bihr, bfr, d0), giz0 = f4axpy(bihz, bfz, d0), gig0 = f4axpy(bihg, bfg, d0);
        float4 gir1 = f4axpy(bihr, bfr, d1), giz1 = f4axpy(bihz, bfz, d1), gig1 = f4axpy(bihg, bfg, d1);
        float4 ghr0 = bhr, ghz0 = bhz, ghg0 = bhg;
        float4 ghr1 = bhr, ghz1 = bhz, ghg1 = bhg;
#pragma unroll 4
        for (int k = 0; k < 64; ++k) {
            const float4 wfr = *(const float4*)(wf_s + k * 192 + cq * 4);
            const float4 wfz = *(const float4*)(wf_s + k * 192 + 64 + cq * 4);
            const float4 wfg = *(const float4*)(wf_s + k * 192 + 128 + cq * 4);
            const float4 whr = *(const float4*)(wh_s + k * 192 + cq * 4);
            const float4 whz = *(const float4*)(wh_s + k * 192 + 64 + cq * 4);
            const float4 whg = *(const float4*)(wh_s + k * 192 + 128 + cq * 4);
            const float a0 = a_s[n0 * 68 + k], a1 = a_s[n1 * 68 + k];
            const float hh0 = h_s[n0 * 68 + k], hh1 = h_s[n1 * 68 + k];
            gir0 = f4fma(gir0, wfr, a0);
            giz0 = f4fma(giz0, wfz, a0);
            gig0 = f4fma(gig0, wfg, a0);
            ghr0 = f4fma(ghr0, whr, hh0);
            ghz0 = f4fma(ghz0, whz, hh0);
            ghg0 = f4fma(ghg0, whg, hh0);
            gir1 = f4fma(gir1, wfr, a1);
            giz1 = f4fma(giz1, wfz, a1);
            gig1 = f4fma(gig1, wfg, a1);
            ghr1 = f4fma(ghr1, whr, hh1);
            ghz1 = f4fma(ghz1, whz, hh1);
            ghg1 = f4fma(ghg1, whg, hh1);
        }
        float4* hout4 = (float4*)h;
        if (base + n0 < NN) {
            float4 r, z, ng, hn;
            r.x = sig1(gir0.x + ghr0.x); r.y = sig1(gir0.y + ghr0.y); r.z = sig1(gir0.z + ghr0.z); r.w = sig1(gir0.w + ghr0.w);
            z.x = sig1(giz0.x + ghz0.x); z.y = sig1(giz0.y + ghz0.y); z.z = sig1(giz0.z + ghz0.z); z.w = sig1(giz0.w + ghz0.w);
            ng.x = tanh1(fmaf(r.x, ghg0.x, gig0.x)); ng.y = tanh1(fmaf(r.y, ghg0.y, gig0.y));
            ng.z = tanh1(fmaf(r.z, ghg0.z, gig0.z)); ng.w = tanh1(fmaf(r.w, ghg0.w, gig0.w));
            const float4 hold = *(const float4*)(h_s + n0 * 68 + cq * 4);
            hn.x = (1.f - z.x) * ng.x + z.x * hold.x; hn.y = (1.f - z.y) * ng.y + z.y * hold.y;
            hn.z = (1.f - z.z) * ng.z + z.z * hold.z; hn.w = (1.f - z.w) * ng.w + z.w * hold.w;
            hout4[(base + n0) * 16 + cq] = hn;
        }
        if (base + n1 < NN) {
            float4 r, z, ng, hn;
            r.x = sig1(gir1.x + ghr1.x); r.y = sig1(gir1.y + ghr1.y); r.z = sig1(gir1.z + ghr1.z); r.w = sig1(gir1.w + ghr1.w);
            z.x = sig1(giz1.x + ghz1.x); z.y = sig1(giz1.y + ghz1.y); z.z = sig1(giz1.z + ghz1.z); z.w = sig1(giz1.w + ghz1.w);
            ng.x = tanh1(fmaf(r.x, ghg1.x, gig1.x)); ng.y = tanh1(fmaf(r.y, ghg1.y, gig1.y));
            ng.z = tanh1(fmaf(r.z, ghg1.z, gig1.z)); ng.w = tanh1(fmaf(r.w, ghg1.w, gig1.w));
            const float4 hold = *(const float4*)(h_s + n1 * 68 + cq * 4);
            hn.x = (1.f - z.x) * ng.x + z.x * hold.x; hn.y = (1.f - z.y) * ng.y + z.y * hold.y;
            hn.z = (1.f - z.z) * ng.z + z.z * hold.z; hn.w = (1.f - z.w) * ng.w + z.w * hold.w;
            hout4[(base + n1) * 16 + cq] = hn;
        }
    }
}

// ---- X[b, g*64 + j] = h[prop[b]][j] ----
__global__ __launch_bounds__(256) void gather_kernel(
    const int* __restrict__ prop, const float* __restrict__ h, float* __restrict__ X, int g) {
    const int b = blockIdx.x * 4 + (threadIdx.x >> 6);
    const int j = threadIdx.x & 63;
    X[b * 128 + g * 64 + j] = h[prop[b] * 64 + j];
}

// ---- hidden = relu(X@W1+b1); z = hidden@W2+b2; out[b]=sigmoid(z); zbuf[b]=z ----
__global__ __launch_bounds__(256) void mlp_kernel(
    const float* __restrict__ X, const float* __restrict__ W1, const float* __restrict__ b1,
    const float* __restrict__ W2, const float* __restrict__ b2,
    float* __restrict__ out, float* __restrict__ zbuf) {
    const int b = blockIdx.x * 4 + (threadIdx.x >> 6);
    const int j = threadIdx.x & 63;
    const float* x = X + b * 128;
    float acc = b1[j];
#pragma unroll 4
    for (int k = 0; k < 128; ++k) acc = fmaf(x[k], W1[k * 64 + j], acc);
    float v = fmaxf(acc, 0.f) * W2[j];
#pragma unroll
    for (int off = 32; off > 0; off >>= 1) v += __shfl_down(v, off);
    if (j == 0) {
        const float z = v + b2[0];
        out[b] = 1.f / (1.f + expf(-z));
        zbuf[b] = z;
    }
}

// ---- loss = -mean(y*logsig(z) + (1-y)*logsig(-z)) -> out[BT] ----
__global__ __launch_bounds__(256) void loss_kernel(
    const float* __restrict__ zbuf, const int* __restrict__ labels, float* __restrict__ out) {
    __shared__ float red[256];
    const int t = threadIdx.x;
    float s = 0.f;
    for (int i = t; i < BT; i += 256) {
        const float z = zbuf[i];
        const float y = (float)labels[i];
        const float lsp = (z >= 0.f) ? -log1pf(expf(-z)) : (z - log1pf(expf(z)));  // log sigmoid(z)
        const float lsn = lsp - z;                                                  // log sigmoid(-z)
        s += y * lsp + (1.f - y) * lsn;
    }
    red[t] = s;
    __syncthreads();
    for (int off = 128; off > 0; off >>= 1) {
        if (t < off) red[t] += red[t + off];
        __syncthreads();
    }
    if (t == 0) out[BT] = -red[0] / (float)BT;
}

extern "C" void kernel_launch(void* const* d_in, const int* in_sizes, int n_in,
                              void* d_out, int out_size, void* d_ws, size_t ws_size,
                              hipStream_t stream) {
    char* ws = (char*)d_ws;
    float* h = (float*)(ws);                  // 25,600,000 B
    float* agg = (float*)(ws + 25600000);     // 25,600,000 B
    float* deg = (float*)(ws + 51200000);     // 400,000 B
    float* Wf = (float*)(ws + 51600000);      // 98,304 B
    float* bf = (float*)(ws + 51698304);      // 1,536 B
    float* X = (float*)(ws + 51699840);       // 2,097,152 B
    float* zbuf = (float*)(ws + 53796992);    // 16,384 B
    float* out = (float*)d_out;

    const float* emb_table = (const float*)d_in[7];
    const float* Wp = (const float*)d_in[8];
    const float* bp = (const float*)d_in[9];

    hipMemsetAsync(agg, 0, (size_t)NN * 64 * 4, stream);
    fusew_kernel<<<16, 256, 65536, stream>>>(
        (const float*)d_in[10], (const float*)d_in[12], (const float*)d_in[11],
        (const float*)d_in[16], (const float*)d_in[18], (const float*)d_in[17], Wf, bf);

    for (int g = 0; g < 2; ++g) {
        const int* adjg = (const int*)d_in[2 + g];
        hipMemsetAsync(deg, 0, (size_t)NN * 4, stream);
        deg_kernel<<<(NE + 255) / 256, 256, 0, stream>>>(adjg, deg);
        embed_kernel<<<NN / 4, 256, 0, stream>>>((const int*)d_in[g], emb_table, Wp, bp, h);
        for (int l = 0; l < 2; ++l) {
            const float* Whh = (const float*)d_in[13 + 6 * l];
            const float* bih = (const float*)d_in[14 + 6 * l];
            const float* bhh = (const float*)d_in[15 + 6 * l];
            for (int ts = 0; ts < 3; ++ts) {
                scatter_kernel<<<NE / 16, 256, 0, stream>>>(adjg, h, agg);
                gru_kernel<<<256, 512, 133376, stream>>>(h, agg, deg, Wf + l * 12288, bf + l * 192,
                                                         bih, Whh, bhh);
            }
        }
        gather_kernel<<<BT / 4, 256, 0, stream>>>((const int*)d_in[4 + g], h, X, g);
    }
    mlp_kernel<<<BT / 4, 256, 0, stream>>>(X, (const float*)d_in[22], (const float*)d_in[23],
                                           (const float*)d_in[24], (const float*)d_in[25], out, zbuf);
    loss_kernel<<<1, 256, 0, stream>>>(zbuf, (const int*)d_in[6], out);
}

// Round 2
// 2756.495 us; speedup vs baseline: 5.0717x; 5.0717x over previous
//
#include <hip/hip_runtime.h>
#include <math.h>

#define NN 100000
#define NE 1200000
#define EMBD 100
#define HD 64
#define BT 4096

__device__ __forceinline__ float4 f4zero() { return make_float4(0.f, 0.f, 0.f, 0.f); }
__device__ __forceinline__ float4 f4fma(float4 acc, float4 w, float s) {
    acc.x = fmaf(w.x, s, acc.x);
    acc.y = fmaf(w.y, s, acc.y);
    acc.z = fmaf(w.z, s, acc.z);
    acc.w = fmaf(w.w, s, acc.w);
    return acc;
}
__device__ __forceinline__ float4 f4axpy(float4 b, float4 x, float s) { // b + s*x
    return make_float4(fmaf(s, x.x, b.x), fmaf(s, x.y, b.y), fmaf(s, x.z, b.z), fmaf(s, x.w, b.w));
}
__device__ __forceinline__ float sig1(float x) { return 1.f / (1.f + __expf(-x)); }
__device__ __forceinline__ float tanh1(float x) {
    x = fminf(fmaxf(x, -15.f), 15.f);
    float e = __expf(2.f * x);
    return (e - 1.f) / (e + 1.f);
}

// ---- precompute Wf[l] = Wm[l] @ Wih[l] (64x192), bf[l] = bm[l] @ Wih[l] (192) ----
__global__ __launch_bounds__(256) void fusew_kernel(
    const float* __restrict__ Wm0, const float* __restrict__ Wih0, const float* __restrict__ bm0,
    const float* __restrict__ Wm1, const float* __restrict__ Wih1, const float* __restrict__ bm1,
    float* __restrict__ Wf, float* __restrict__ bf) {
    extern __shared__ float lds[];
    float* wm_s = lds;          // 4096
    float* wih_s = lds + 4096;  // 12288
    const int l = blockIdx.x >> 3, slice = blockIdx.x & 7;
    const float* Wm = l ? Wm1 : Wm0;
    const float* Wih = l ? Wih1 : Wih0;
    const float* bm = l ? bm1 : bm0;
    for (int i = threadIdx.x; i < 4096; i += 256) wm_s[i] = Wm[i];
    for (int i = threadIdx.x; i < 12288; i += 256) wih_s[i] = Wih[i];
    __syncthreads();
    float* Wfl = Wf + l * 12288;
    float* bfl = bf + l * 192;
    const int o0 = slice * 1536;
    for (int o = o0 + threadIdx.x; o < o0 + 1536; o += 256) {
        int r = o / 192, c = o % 192;
        float s = 0.f;
        for (int k = 0; k < 64; ++k) s = fmaf(wm_s[r * 64 + k], wih_s[k * 192 + c], s);
        Wfl[o] = s;
    }
    const int c0 = slice * 24;
    for (int c = c0 + threadIdx.x; c < c0 + 24; c += 256) {
        float s = 0.f;
        for (int k = 0; k < 64; ++k) s = fmaf(bm[k], wih_s[k * 192 + c], s);
        bfl[c] = s;
    }
}

// ---- h[n] = emb_table[ind[n]] @ Wp + bp ----
__global__ __launch_bounds__(256) void embed_kernel(
    const int* __restrict__ ind, const float* __restrict__ emb,
    const float* __restrict__ Wp, const float* __restrict__ bp, float* __restrict__ h) {
    const int node = blockIdx.x * 4 + (threadIdx.x >> 6);
    const int j = threadIdx.x & 63;
    const int idx = ind[node];
    const float* e = emb + idx * EMBD;
    float acc = bp[j];
#pragma unroll 4
    for (int k = 0; k < EMBD; ++k) acc = fmaf(e[k], Wp[k * 64 + j], acc);
    h[node * 64 + j] = acc;
}

// ---- CSR build: histogram of in-degree into rowptr (pre-zeroed) ----
__global__ __launch_bounds__(256) void hist_kernel(const int* __restrict__ adj, int* __restrict__ rowptr) {
    const int e = blockIdx.x * 256 + threadIdx.x;
    if (e < NE) atomicAdd(&rowptr[adj[2 * e + 1]], 1);
}

// ---- CSR build: in-place exclusive prefix scan over rowptr[0..NN) (single block) ----
__global__ __launch_bounds__(1024) void scan_kernel(int* __restrict__ rowptr) {
    __shared__ int sums[1024];
    const int t = threadIdx.x;
    const int chunk = 98;  // 1024*98 = 100352 >= NN
    const int i0 = t * chunk;
    int s = 0;
    for (int i = i0; i < i0 + chunk && i < NN; ++i) s += rowptr[i];
    sums[t] = s;
    __syncthreads();
    for (int off = 1; off < 1024; off <<= 1) {
        int v = (t >= off) ? sums[t - off] : 0;
        __syncthreads();
        sums[t] += v;
        __syncthreads();
    }
    int run = (t == 0) ? 0 : sums[t - 1];
    for (int i = i0; i < i0 + chunk && i < NN; ++i) {
        int v = rowptr[i];
        rowptr[i] = run;
        run += v;
    }
}

// ---- CSR build: fill. Uses rowptr as cursor; afterwards rowptr[n] == end offset of node n ----
__global__ __launch_bounds__(256) void fill_kernel(
    const int* __restrict__ adj, int* __restrict__ rowptr, int* __restrict__ csr) {
    const int e = blockIdx.x * 256 + threadIdx.x;
    if (e < NE) {
        const int2 st = ((const int2*)adj)[e];
        const int pos = atomicAdd(&rowptr[st.y], 1);
        csr[pos] = st.x;
    }
}

// ---- agg[n] = sum over in-edges of h[src]; also deg[n]. 16 lanes x float4 per node. ----
// rowptr is the SHIFTED array: range for node n is [ (n ? rowptr[n-1] : 0), rowptr[n] )
__global__ __launch_bounds__(256) void agg_kernel(
    const int* __restrict__ rowptr, const int* __restrict__ csr,
    const float* __restrict__ h, float* __restrict__ agg, float* __restrict__ deg) {
    const int t = threadIdx.x;
    const int node = blockIdx.x * 16 + (t >> 4);
    const int c = t & 15;
    const int start = node ? rowptr[node - 1] : 0;
    const int end = rowptr[node];
    const float4* h4 = (const float4*)h;
    float4 acc = f4zero();
    for (int e = start; e < end; ++e) {
        const int src = csr[e];
        const float4 v = h4[src * 16 + c];
        acc.x += v.x;
        acc.y += v.y;
        acc.z += v.z;
        acc.w += v.w;
    }
    ((float4*)agg)[node * 16 + c] = acc;
    if (c == 0) deg[node] = (float)(end - start);
}

// ---- fused: gi = agg@Wf + deg*bf + bih ; gh = h@Whh + bhh ; GRU elementwise -> h (in place)
__global__ __launch_bounds__(512) void gru_kernel(
    float* __restrict__ h, const float* __restrict__ agg, const float* __restrict__ deg,
    const float* __restrict__ Wf, const float* __restrict__ bf,
    const float* __restrict__ bih, const float* __restrict__ Whh, const float* __restrict__ bhh) {
    extern __shared__ float lds[];
    float* wf_s = lds;           // 12288
    float* wh_s = lds + 12288;   // 12288
    float* a_s = lds + 24576;    // 64*68 = 4352
    float* h_s = lds + 28928;    // 4352
    float* deg_s = lds + 33280;  // 64
    const int t = threadIdx.x;
    const int cq = t & 15;   // col-quad 0..15
    const int np = t >> 4;   // node-pair 0..31
    {
        const float4* wf4 = (const float4*)Wf;
        const float4* wh4 = (const float4*)Whh;
        float4* wfs4 = (float4*)wf_s;
        float4* whs4 = (float4*)wh_s;
        for (int i = t; i < 3072; i += 512) {
            wfs4[i] = wf4[i];
            whs4[i] = wh4[i];
        }
    }
    const float4* bih4 = (const float4*)bih;
    const float4* bf4p = (const float4*)bf;
    const float4* bhh4 = (const float4*)bhh;
    const float4 bihr = bih4[cq], bihz = bih4[16 + cq], bihg = bih4[32 + cq];
    const float4 bfr = bf4p[cq], bfz = bf4p[16 + cq], bfg = bf4p[32 + cq];
    const float4 bhr = bhh4[cq], bhz = bhh4[16 + cq], bhg = bhh4[32 + cq];
    const int n0 = 2 * np, n1 = 2 * np + 1;

    for (int tile = blockIdx.x; tile * 64 < NN; tile += gridDim.x) {
        const int base = tile * 64;
        __syncthreads();
        {
            const float4* agg4 = (const float4*)agg;
            const float4* h4 = (const float4*)h;
            for (int i = t; i < 1024; i += 512) {
                const int r = i >> 4, c = i & 15;
                const int node = base + r;
                float4 va = f4zero(), vh = f4zero();
                if (node < NN) {
                    va = agg4[node * 16 + c];
                    vh = h4[node * 16 + c];
                }
                *(float4*)(a_s + r * 68 + c * 4) = va;
                *(float4*)(h_s + r * 68 + c * 4) = vh;
            }
            if (t < 64) deg_s[t] = (base + t < NN) ? deg[base + t] : 0.f;
        }
        __syncthreads();
        const float d0 = deg_s[n0], d1 = deg_s[n1];
        float4 gir0 = f4axpy(bihr, bfr, d0), giz0 = f4axpy(bihz, bfz, d0), gig0 = f4axpy(bihg, bfg, d0);
        float4 gir1 = f4axpy(bihr, bfr, d1), giz1 = f4axpy(bihz, bfz, d1), gig1 = f4axpy(bihg, bfg, d1);
        float4 ghr0 = bhr, ghz0 = bhz, ghg0 = bhg;
        float4 ghr1 = bhr, ghz1 = bhz, ghg1 = bhg;
#pragma unroll 4
        for (int k = 0; k < 64; ++k) {
            const float4 wfr = *(const float4*)(wf_s + k * 192 + cq * 4);
            const float4 wfz = *(const float4*)(wf_s + k * 192 + 64 + cq * 4);
            const float4 wfg = *(const float4*)(wf_s + k * 192 + 128 + cq * 4);
            const float4 whr = *(const float4*)(wh_s + k * 192 + cq * 4);
            const float4 whz = *(const float4*)(wh_s + k * 192 + 64 + cq * 4);
            const float4 whg = *(const float4*)(wh_s + k * 192 + 128 + cq * 4);
            const float a0 = a_s[n0 * 68 + k], a1 = a_s[n1 * 68 + k];
            const float hh0 = h_s[n0 * 68 + k], hh1 = h_s[n1 * 68 + k];
            gir0 = f4fma(gir0, wfr, a0);
            giz0 = f4fma(giz0, wfz, a0);
            gig0 = f4fma(gig0, wfg, a0);
            ghr0 = f4fma(ghr0, whr, hh0);
            ghz0 = f4fma(ghz0, whz, hh0);
            ghg0 = f4fma(ghg0, whg, hh0);
            gir1 = f4fma(gir1, wfr, a1);
            giz1 = f4fma(giz1, wfz, a1);
            gig1 = f4fma(gig1, wfg, a1);
            ghr1 = f4fma(ghr1, whr, hh1);
            ghz1 = f4fma(ghz1, whz, hh1);
            ghg1 = f4fma(ghg1, whg, hh1);
        }
        float4* hout4 = (float4*)h;
        if (base + n0 < NN) {
            float4 r, z, ng, hn;
            r.x = sig1(gir0.x + ghr0.x); r.y = sig1(gir0.y + ghr0.y); r.z = sig1(gir0.z + ghr0.z); r.w = sig1(gir0.w + ghr0.w);
            z.x = sig1(giz0.x + ghz0.x); z.y = sig1(giz0.y + ghz0.y); z.z = sig1(giz0.z + ghz0.z); z.w = sig1(giz0.w + ghz0.w);
            ng.x = tanh1(fmaf(r.x, ghg0.x, gig0.x)); ng.y = tanh1(fmaf(r.y, ghg0.y, gig0.y));
            ng.z = tanh1(fmaf(r.z, ghg0.z, gig0.z)); ng.w = tanh1(fmaf(r.w, ghg0.w, gig0.w));
            const float4 hold = *(const float4*)(h_s + n0 * 68 + cq * 4);
            hn.x = (1.f - z.x) * ng.x + z.x * hold.x; hn.y = (1.f - z.y) * ng.y + z.y * hold.y;
            hn.z = (1.f - z.z) * ng.z + z.z * hold.z; hn.w = (1.f - z.w) * ng.w + z.w * hold.w;
            hout4[(base + n0) * 16 + cq] = hn;
        }
        if (base + n1 < NN) {
            float4 r, z, ng, hn;
            r.x = sig1(gir1.x + ghr1.x); r.y = sig1(gir1.y + ghr1.y); r.z = sig1(gir1.z + ghr1.z); r.w = sig1(gir1.w + ghr1.w);
            z.x = sig1(giz1.x + ghz1.x); z.y = sig1(giz1.y + ghz1.y); z.z = sig1(giz1.z + ghz1.z); z.w = sig1(giz1.w + ghz1.w);
            ng.x = tanh1(fmaf(r.x, ghg1.x, gig1.x)); ng.y = tanh1(fmaf(r.y, ghg1.y, gig1.y));
            ng.z = tanh1(fmaf(r.z, ghg1.z, gig1.z)); ng.w = tanh1(fmaf(r.w, ghg1.w, gig1.w));
            const float4 hold = *(const float4*)(h_s + n1 * 68 + cq * 4);
            hn.x = (1.f - z.x) * ng.x + z.x * hold.x; hn.y = (1.f - z.y) * ng.y + z.y * hold.y;
            hn.z = (1.f - z.z) * ng.z + z.z * hold.z; hn.w = (1.f - z.w) * ng.w + z.w * hold.w;
            hout4[(base + n1) * 16 + cq] = hn;
        }
    }
}

// ---- X[b, g*64 + j] = h[prop[b]][j] ----
__global__ __launch_bounds__(256) void gather_kernel(
    const int* __restrict__ prop, const float* __restrict__ h, float* __restrict__ X, int g) {
    const int b = blockIdx.x * 4 + (threadIdx.x >> 6);
    const int j = threadIdx.x & 63;
    X[b * 128 + g * 64 + j] = h[prop[b] * 64 + j];
}

// ---- hidden = relu(X@W1+b1); z = hidden@W2+b2; out[b]=sigmoid(z); zbuf[b]=z ----
__global__ __launch_bounds__(256) void mlp_kernel(
    const float* __restrict__ X, const float* __restrict__ W1, const float* __restrict__ b1,
    const float* __restrict__ W2, const float* __restrict__ b2,
    float* __restrict__ out, float* __restrict__ zbuf) {
    const int b = blockIdx.x * 4 + (threadIdx.x >> 6);
    const int j = threadIdx.x & 63;
    const float* x = X + b * 128;
    float acc = b1[j];
#pragma unroll 4
    for (int k = 0; k < 128; ++k) acc = fmaf(x[k], W1[k * 64 + j], acc);
    float v = fmaxf(acc, 0.f) * W2[j];
#pragma unroll
    for (int off = 32; off > 0; off >>= 1) v += __shfl_down(v, off);
    if (j == 0) {
        const float z = v + b2[0];
        out[b] = 1.f / (1.f + expf(-z));
        zbuf[b] = z;
    }
}

// ---- loss = -mean(y*logsig(z) + (1-y)*logsig(-z)) -> out[BT] ----
__global__ __launch_bounds__(256) void loss_kernel(
    const float* __restrict__ zbuf, const int* __restrict__ labels, float* __restrict__ out) {
    __shared__ float red[256];
    const int t = threadIdx.x;
    float s = 0.f;
    for (int i = t; i < BT; i += 256) {
        const float z = zbuf[i];
        const float y = (float)labels[i];
        const float lsp = (z >= 0.f) ? -log1pf(expf(-z)) : (z - log1pf(expf(z)));
        const float lsn = lsp - z;
        s += y * lsp + (1.f - y) * lsn;
    }
    red[t] = s;
    __syncthreads();
    for (int off = 128; off > 0; off >>= 1) {
        if (t < off) red[t] += red[t + off];
        __syncthreads();
    }
    if (t == 0) out[BT] = -red[0] / (float)BT;
}

extern "C" void kernel_launch(void* const* d_in, const int* in_sizes, int n_in,
                              void* d_out, int out_size, void* d_ws, size_t ws_size,
                              hipStream_t stream) {
    char* ws = (char*)d_ws;
    float* h = (float*)(ws);                  // 25,600,000 B
    float* agg = (float*)(ws + 25600000);     // 25,600,000 B
    float* deg = (float*)(ws + 51200000);     // 400,000 B
    float* Wf = (float*)(ws + 51600000);      // 98,304 B
    float* bf = (float*)(ws + 51698304);      // 1,536 B
    int* rowptr = (int*)(ws + 51699840);      // 400,000 B
    int* csr = (int*)(ws + 52099840);         // 4,800,000 B
    float* X = (float*)(ws + 56899840);       // 2,097,152 B
    float* zbuf = (float*)(ws + 58996992);    // 16,384 B
    float* out = (float*)d_out;

    const float* emb_table = (const float*)d_in[7];
    const float* Wp = (const float*)d_in[8];
    const float* bp = (const float*)d_in[9];

    fusew_kernel<<<16, 256, 65536, stream>>>(
        (const float*)d_in[10], (const float*)d_in[12], (const float*)d_in[11],
        (const float*)d_in[16], (const float*)d_in[18], (const float*)d_in[17], Wf, bf);

    for (int g = 0; g < 2; ++g) {
        const int* adjg = (const int*)d_in[2 + g];
        // CSR build for this graph
        hipMemsetAsync(rowptr, 0, (size_t)NN * 4, stream);
        hist_kernel<<<(NE + 255) / 256, 256, 0, stream>>>(adjg, rowptr);
        scan_kernel<<<1, 1024, 0, stream>>>(rowptr);
        fill_kernel<<<(NE + 255) / 256, 256, 0, stream>>>(adjg, rowptr, csr);

        embed_kernel<<<NN / 4, 256, 0, stream>>>((const int*)d_in[g], emb_table, Wp, bp, h);
        for (int l = 0; l < 2; ++l) {
            const float* Whh = (const float*)d_in[13 + 6 * l];
            const float* bih = (const float*)d_in[14 + 6 * l];
            const float* bhh = (const float*)d_in[15 + 6 * l];
            for (int ts = 0; ts < 3; ++ts) {
                agg_kernel<<<NN / 16, 256, 0, stream>>>(rowptr, csr, h, agg, deg);
                gru_kernel<<<256, 512, 133376, stream>>>(h, agg, deg, Wf + l * 12288, bf + l * 192,
                                                         bih, Whh, bhh);
            }
        }
        gather_kernel<<<BT / 4, 256, 0, stream>>>((const int*)d_in[4 + g], h, X, g);
    }
    mlp_kernel<<<BT / 4, 256, 0, stream>>>(X, (const float*)d_in[22], (const float*)d_in[23],
                                           (const float*)d_in[24], (const float*)d_in[25], out, zbuf);
    loss_kernel<<<1, 256, 0, stream>>>(zbuf, (const int*)d_in[6], out);
}

// Round 3
// 2136.624 us; speedup vs baseline: 6.5431x; 1.2901x over previous
//
#include <hip/hip_runtime.h>
#include <math.h>

#define NN 100000
#define NE 1200000
#define EMBD 100
#define HD 64
#define BT 4096
#define SCAN_B 98  // 98 * 1024 >= NN

__device__ __forceinline__ float4 f4zero() { return make_float4(0.f, 0.f, 0.f, 0.f); }
__device__ __forceinline__ float4 f4fma(float4 acc, float4 w, float s) {
    acc.x = fmaf(w.x, s, acc.x);
    acc.y = fmaf(w.y, s, acc.y);
    acc.z = fmaf(w.z, s, acc.z);
    acc.w = fmaf(w.w, s, acc.w);
    return acc;
}
__device__ __forceinline__ float4 f4axpy(float4 b, float4 x, float s) { // b + s*x
    return make_float4(fmaf(s, x.x, b.x), fmaf(s, x.y, b.y), fmaf(s, x.z, b.z), fmaf(s, x.w, b.w));
}
__device__ __forceinline__ float sig1(float x) { return 1.f / (1.f + __expf(-x)); }
__device__ __forceinline__ float tanh1(float x) {
    x = fminf(fmaxf(x, -15.f), 15.f);
    float e = __expf(2.f * x);
    return (e - 1.f) / (e + 1.f);
}
// f32 -> bf16 (round-to-nearest-even), and bf16 -> f32 unpack helpers
__device__ __forceinline__ unsigned short f2b(float f) {
    unsigned u = __float_as_uint(f);
    u += 0x7fffu + ((u >> 16) & 1u);
    return (unsigned short)(u >> 16);
}
__device__ __forceinline__ float blo(unsigned u) { return __uint_as_float(u << 16); }
__device__ __forceinline__ float bhi(unsigned u) { return __uint_as_float(u & 0xffff0000u); }
__device__ __forceinline__ unsigned packb(float lo, float hi) {
    return (unsigned)f2b(lo) | ((unsigned)f2b(hi) << 16);
}

// ---- precompute Wf[l] = Wm[l] @ Wih[l] (64x192), bf[l] = bm[l] @ Wih[l] (192) ----
__global__ __launch_bounds__(256) void fusew_kernel(
    const float* __restrict__ Wm0, const float* __restrict__ Wih0, const float* __restrict__ bm0,
    const float* __restrict__ Wm1, const float* __restrict__ Wih1, const float* __restrict__ bm1,
    float* __restrict__ Wf, float* __restrict__ bf) {
    extern __shared__ float lds[];
    float* wm_s = lds;          // 4096
    float* wih_s = lds + 4096;  // 12288
    const int l = blockIdx.x >> 3, slice = blockIdx.x & 7;
    const float* Wm = l ? Wm1 : Wm0;
    const float* Wih = l ? Wih1 : Wih0;
    const float* bm = l ? bm1 : bm0;
    for (int i = threadIdx.x; i < 4096; i += 256) wm_s[i] = Wm[i];
    for (int i = threadIdx.x; i < 12288; i += 256) wih_s[i] = Wih[i];
    __syncthreads();
    float* Wfl = Wf + l * 12288;
    float* bfl = bf + l * 192;
    const int o0 = slice * 1536;
    for (int o = o0 + threadIdx.x; o < o0 + 1536; o += 256) {
        int r = o / 192, c = o % 192;
        float s = 0.f;
        for (int k = 0; k < 64; ++k) s = fmaf(wm_s[r * 64 + k], wih_s[k * 192 + c], s);
        Wfl[o] = s;
    }
    const int c0 = slice * 24;
    for (int c = c0 + threadIdx.x; c < c0 + 24; c += 256) {
        float s = 0.f;
        for (int k = 0; k < 64; ++k) s = fmaf(bm[k], wih_s[k * 192 + c], s);
        bfl[c] = s;
    }
}

// ---- h[n] = emb_table[ind[n]] @ Wp + bp ; also bf16 mirror hb ----
__global__ __launch_bounds__(256) void embed_kernel(
    const int* __restrict__ ind, const float* __restrict__ emb,
    const float* __restrict__ Wp, const float* __restrict__ bp,
    float* __restrict__ h, unsigned short* __restrict__ hb) {
    const int node = blockIdx.x * 4 + (threadIdx.x >> 6);
    const int j = threadIdx.x & 63;
    const int idx = ind[node];
    const float* e = emb + idx * EMBD;
    float acc = bp[j];
#pragma unroll 4
    for (int k = 0; k < EMBD; ++k) acc = fmaf(e[k], Wp[k * 64 + j], acc);
    h[node * 64 + j] = acc;
    hb[node * 64 + j] = f2b(acc);
}

// ---- CSR build: histogram of in-degree into rowptr (pre-zeroed) ----
__global__ __launch_bounds__(256) void hist_kernel(const int* __restrict__ adj, int* __restrict__ rowptr) {
    const int e = blockIdx.x * 256 + threadIdx.x;
    if (e < NE) atomicAdd(&rowptr[adj[2 * e + 1]], 1);
}

// ---- hierarchical exclusive scan over rowptr ----
__global__ __launch_bounds__(256) void scan1_kernel(const int* __restrict__ rowptr, int* __restrict__ bsum) {
    __shared__ int red[256];
    const int t = threadIdx.x, b = blockIdx.x;
    const int base = b * 1024;
    int s = 0;
    for (int i = t; i < 1024; i += 256) {
        const int idx = base + i;
        s += (idx < NN) ? rowptr[idx] : 0;
    }
    red[t] = s;
    __syncthreads();
    for (int off = 128; off > 0; off >>= 1) {
        if (t < off) red[t] += red[t + off];
        __syncthreads();
    }
    if (t == 0) bsum[b] = red[0];
}

__global__ __launch_bounds__(128) void scan2_kernel(int* __restrict__ bsum) {
    __shared__ int s[128];
    const int t = threadIdx.x;
    const int v = (t < SCAN_B) ? bsum[t] : 0;
    s[t] = v;
    __syncthreads();
    for (int off = 1; off < 128; off <<= 1) {
        const int x = (t >= off) ? s[t - off] : 0;
        __syncthreads();
        s[t] += x;
        __syncthreads();
    }
    if (t < SCAN_B) bsum[t] = s[t] - v;  // exclusive
}

__global__ __launch_bounds__(256) void scan3_kernel(int* __restrict__ rowptr, const int* __restrict__ bsum,
                                                    float* __restrict__ deg) {
    __shared__ int red[256];
    const int t = threadIdx.x, b = blockIdx.x;
    const int i0 = b * 1024 + t * 4;
    int v[4];
#pragma unroll
    for (int j = 0; j < 4; ++j) v[j] = (i0 + j < NN) ? rowptr[i0 + j] : 0;
    const int ts = v[0] + v[1] + v[2] + v[3];
    red[t] = ts;
    __syncthreads();
    for (int off = 1; off < 256; off <<= 1) {
        const int x = (t >= off) ? red[t - off] : 0;
        __syncthreads();
        red[t] += x;
        __syncthreads();
    }
    int pre = bsum[b] + red[t] - ts;  // exclusive prefix for this thread
#pragma unroll
    for (int j = 0; j < 4; ++j) {
        if (i0 + j < NN) {
            rowptr[i0 + j] = pre;
            deg[i0 + j] = (float)v[j];
            pre += v[j];
        }
    }
}

// ---- CSR build: fill. Uses rowptr as cursor; afterwards rowptr[n] == end offset of node n ----
__global__ __launch_bounds__(256) void fill_kernel(
    const int* __restrict__ adj, int* __restrict__ rowptr, int* __restrict__ csr) {
    const int e = blockIdx.x * 256 + threadIdx.x;
    if (e < NE) {
        const int2 st = ((const int2*)adj)[e];
        const int pos = atomicAdd(&rowptr[st.y], 1);
        csr[pos] = st.x;
    }
}

// ---- aggb[n] = bf16( sum over in-edges of hb[src] ). 8 lanes x 8 bf16 per node. ----
// rowptr is the SHIFTED array: range for node n is [ (n ? rowptr[n-1] : 0), rowptr[n] )
__global__ __launch_bounds__(256) void agg_kernel(
    const int* __restrict__ rowptr, const int* __restrict__ csr,
    const unsigned short* __restrict__ hb, unsigned short* __restrict__ aggb) {
    const int t = threadIdx.x;
    const int node = blockIdx.x * 32 + (t >> 3);
    const int c = t & 7;
    const int start = node ? rowptr[node - 1] : 0;
    const int end = rowptr[node];
    float acc[8];
#pragma unroll
    for (int j = 0; j < 8; ++j) acc[j] = 0.f;
    int e = start;
    for (; e + 1 < end; e += 2) {
        const int s0 = csr[e], s1 = csr[e + 1];
        const uint4 u0 = *(const uint4*)(hb + s0 * 64 + c * 8);
        const uint4 u1 = *(const uint4*)(hb + s1 * 64 + c * 8);
        acc[0] += blo(u0.x); acc[1] += bhi(u0.x); acc[2] += blo(u0.y); acc[3] += bhi(u0.y);
        acc[4] += blo(u0.z); acc[5] += bhi(u0.z); acc[6] += blo(u0.w); acc[7] += bhi(u0.w);
        acc[0] += blo(u1.x); acc[1] += bhi(u1.x); acc[2] += blo(u1.y); acc[3] += bhi(u1.y);
        acc[4] += blo(u1.z); acc[5] += bhi(u1.z); acc[6] += blo(u1.w); acc[7] += bhi(u1.w);
    }
    if (e < end) {
        const int s0 = csr[e];
        const uint4 u0 = *(const uint4*)(hb + s0 * 64 + c * 8);
        acc[0] += blo(u0.x); acc[1] += bhi(u0.x); acc[2] += blo(u0.y); acc[3] += bhi(u0.y);
        acc[4] += blo(u0.z); acc[5] += bhi(u0.z); acc[6] += blo(u0.w); acc[7] += bhi(u0.w);
    }
    uint4 o;
    o.x = packb(acc[0], acc[1]);
    o.y = packb(acc[2], acc[3]);
    o.z = packb(acc[4], acc[5]);
    o.w = packb(acc[6], acc[7]);
    *(uint4*)(aggb + node * 64 + c * 8) = o;
}

// ---- fused GRU: gi = agg@Wf + deg*bf + bih ; gh = h@Whh + bhh ; elementwise -> h, hb
// 128-node tiles, 4 nodes/thread, a/h tiles bf16 k-major in LDS, weights fp32 in LDS.
__global__ __launch_bounds__(512, 1) void gru_kernel(
    float* __restrict__ h, unsigned short* __restrict__ hb,
    const unsigned short* __restrict__ aggb, const float* __restrict__ deg,
    const float* __restrict__ Wf, const float* __restrict__ bf,
    const float* __restrict__ bih, const float* __restrict__ Whh, const float* __restrict__ bhh) {
    extern __shared__ float lds[];
    float* wf_s = lds;                                      // 12288 f32
    float* wh_s = lds + 12288;                              // 12288 f32
    unsigned short* a_s = (unsigned short*)(lds + 24576);   // [64][128] bf16
    unsigned short* h_s = a_s + 8192;                       // [64][128] bf16
    const int t = threadIdx.x;
    const int cq = t & 15;        // col-quad within each 64-wide gate
    const int n0 = (t >> 4) * 4;  // first of this thread's 4 nodes within tile
    // stage weights once per block
    for (int i = t; i < 3072; i += 512) {
        ((float4*)wf_s)[i] = ((const float4*)Wf)[i];
        ((float4*)wh_s)[i] = ((const float4*)Whh)[i];
    }
    const float4 bihr = ((const float4*)bih)[cq], bihz = ((const float4*)bih)[16 + cq], bihg = ((const float4*)bih)[32 + cq];
    const float4 bfr = ((const float4*)bf)[cq], bfz = ((const float4*)bf)[16 + cq], bfg = ((const float4*)bf)[32 + cq];
    const float4 bhr = ((const float4*)bhh)[cq], bhz = ((const float4*)bhh)[16 + cq], bhg = ((const float4*)bhh)[32 + cq];
    // staging map: node sn (0..127), k-chunk skc*16
    const int sn = t >> 2, skc = (t & 3) * 16;
    const int ntiles = (NN + 127) >> 7;

    for (int tile = blockIdx.x; tile < ntiles; tile += gridDim.x) {
        const int base = tile << 7;
        __syncthreads();
        // ---- stage a_s, h_s (transpose to k-major) ----
        {
            const int node = base + sn;
            uint4 av0 = make_uint4(0, 0, 0, 0), av1 = make_uint4(0, 0, 0, 0);
            float4 hv0 = f4zero(), hv1 = f4zero(), hv2 = f4zero(), hv3 = f4zero();
            if (node < NN) {
                av0 = *(const uint4*)(aggb + node * 64 + skc);
                av1 = *(const uint4*)(aggb + node * 64 + skc + 8);
                const float4* hp = (const float4*)(h + node * 64 + skc);
                hv0 = hp[0]; hv1 = hp[1]; hv2 = hp[2]; hv3 = hp[3];
            }
            const unsigned au[4] = {av0.x, av0.y, av0.z, av0.w};
            const unsigned bu[4] = {av1.x, av1.y, av1.z, av1.w};
#pragma unroll
            for (int j = 0; j < 4; ++j) {
                a_s[(skc + 2 * j) * 128 + sn] = (unsigned short)(au[j] & 0xffffu);
                a_s[(skc + 2 * j + 1) * 128 + sn] = (unsigned short)(au[j] >> 16);
                a_s[(skc + 8 + 2 * j) * 128 + sn] = (unsigned short)(bu[j] & 0xffffu);
                a_s[(skc + 8 + 2 * j + 1) * 128 + sn] = (unsigned short)(bu[j] >> 16);
            }
            const float hf[16] = {hv0.x, hv0.y, hv0.z, hv0.w, hv1.x, hv1.y, hv1.z, hv1.w,
                                  hv2.x, hv2.y, hv2.z, hv2.w, hv3.x, hv3.y, hv3.z, hv3.w};
#pragma unroll
            for (int j = 0; j < 16; ++j) h_s[(skc + j) * 128 + sn] = f2b(hf[j]);
        }
        __syncthreads();
        // ---- init accumulators ----
        float d[4];
#pragma unroll
        for (int j = 0; j < 4; ++j) d[j] = (base + n0 + j < NN) ? deg[base + n0 + j] : 0.f;
        float4 gir[4], giz[4], gig[4], ghr[4], ghz[4], ghg[4];
#pragma unroll
        for (int j = 0; j < 4; ++j) {
            gir[j] = f4axpy(bihr, bfr, d[j]);
            giz[j] = f4axpy(bihz, bfz, d[j]);
            gig[j] = f4axpy(bihg, bfg, d[j]);
            ghr[j] = bhr; ghz[j] = bhz; ghg[j] = bhg;
        }
        // ---- K loop ----
#pragma unroll 2
        for (int k = 0; k < 64; ++k) {
            const float4 wfr = ((const float4*)(wf_s + k * 192))[cq];
            const float4 wfz = ((const float4*)(wf_s + k * 192 + 64))[cq];
            const float4 wfg = ((const float4*)(wf_s + k * 192 + 128))[cq];
            const float4 whr = ((const float4*)(wh_s + k * 192))[cq];
            const float4 whz = ((const float4*)(wh_s + k * 192 + 64))[cq];
            const float4 whg = ((const float4*)(wh_s + k * 192 + 128))[cq];
            const uint2 au = *(const uint2*)(a_s + k * 128 + n0);
            const uint2 hu = *(const uint2*)(h_s + k * 128 + n0);
            const float a[4] = {blo(au.x), bhi(au.x), blo(au.y), bhi(au.y)};
            const float hh[4] = {blo(hu.x), bhi(hu.x), blo(hu.y), bhi(hu.y)};
#pragma unroll
            for (int j = 0; j < 4; ++j) {
                gir[j] = f4fma(gir[j], wfr, a[j]);
                giz[j] = f4fma(giz[j], wfz, a[j]);
                gig[j] = f4fma(gig[j], wfg, a[j]);
                ghr[j] = f4fma(ghr[j], whr, hh[j]);
                ghz[j] = f4fma(ghz[j], whz, hh[j]);
                ghg[j] = f4fma(ghg[j], whg, hh[j]);
            }
        }
        // ---- epilogue ----
#pragma unroll
        for (int j = 0; j < 4; ++j) {
            const int node = base + n0 + j;
            if (node < NN) {
                const float4 hold = *(const float4*)(h + node * 64 + cq * 4);
                float4 r, z, ng, hn;
                r.x = sig1(gir[j].x + ghr[j].x); r.y = sig1(gir[j].y + ghr[j].y);
                r.z = sig1(gir[j].z + ghr[j].z); r.w = sig1(gir[j].w + ghr[j].w);
                z.x = sig1(giz[j].x + ghz[j].x); z.y = sig1(giz[j].y + ghz[j].y);
                z.z = sig1(giz[j].z + ghz[j].z); z.w = sig1(giz[j].w + ghz[j].w);
                ng.x = tanh1(fmaf(r.x, ghg[j].x, gig[j].x)); ng.y = tanh1(fmaf(r.y, ghg[j].y, gig[j].y));
                ng.z = tanh1(fmaf(r.z, ghg[j].z, gig[j].z)); ng.w = tanh1(fmaf(r.w, ghg[j].w, gig[j].w));
                hn.x = (1.f - z.x) * ng.x + z.x * hold.x; hn.y = (1.f - z.y) * ng.y + z.y * hold.y;
                hn.z = (1.f - z.z) * ng.z + z.z * hold.z; hn.w = (1.f - z.w) * ng.w + z.w * hold.w;
                *(float4*)(h + node * 64 + cq * 4) = hn;
                uint2 p;
                p.x = packb(hn.x, hn.y);
                p.y = packb(hn.z, hn.w);
                *(uint2*)(hb + node * 64 + cq * 4) = p;
            }
        }
    }
}

// ---- X[b, g*64 + j] = h[prop[b]][j] ----
__global__ __launch_bounds__(256) void gather_kernel(
    const int* __restrict__ prop, const float* __restrict__ h, float* __restrict__ X, int g) {
    const int b = blockIdx.x * 4 + (threadIdx.x >> 6);
    const int j = threadIdx.x & 63;
    X[b * 128 + g * 64 + j] = h[prop[b] * 64 + j];
}

// ---- hidden = relu(X@W1+b1); z = hidden@W2+b2; out[b]=sigmoid(z); zbuf[b]=z ----
__global__ __launch_bounds__(256) void mlp_kernel(
    const float* __restrict__ X, const float* __restrict__ W1, const float* __restrict__ b1,
    const float* __restrict__ W2, const float* __restrict__ b2,
    float* __restrict__ out, float* __restrict__ zbuf) {
    const int b = blockIdx.x * 4 + (threadIdx.x >> 6);
    const int j = threadIdx.x & 63;
    const float* x = X + b * 128;
    float acc = b1[j];
#pragma unroll 4
    for (int k = 0; k < 128; ++k) acc = fmaf(x[k], W1[k * 64 + j], acc);
    float v = fmaxf(acc, 0.f) * W2[j];
#pragma unroll
    for (int off = 32; off > 0; off >>= 1) v += __shfl_down(v, off);
    if (j == 0) {
        const float z = v + b2[0];
        out[b] = 1.f / (1.f + expf(-z));
        zbuf[b] = z;
    }
}

// ---- loss = -mean(y*logsig(z) + (1-y)*logsig(-z)) -> out[BT] ----
__global__ __launch_bounds__(256) void loss_kernel(
    const float* __restrict__ zbuf, const int* __restrict__ labels, float* __restrict__ out) {
    __shared__ float red[256];
    const int t = threadIdx.x;
    float s = 0.f;
    for (int i = t; i < BT; i += 256) {
        const float z = zbuf[i];
        const float y = (float)labels[i];
        const float lsp = (z >= 0.f) ? -log1pf(expf(-z)) : (z - log1pf(expf(z)));
        const float lsn = lsp - z;
        s += y * lsp + (1.f - y) * lsn;
    }
    red[t] = s;
    __syncthreads();
    for (int off = 128; off > 0; off >>= 1) {
        if (t < off) red[t] += red[t + off];
        __syncthreads();
    }
    if (t == 0) out[BT] = -red[0] / (float)BT;
}

extern "C" void kernel_launch(void* const* d_in, const int* in_sizes, int n_in,
                              void* d_out, int out_size, void* d_ws, size_t ws_size,
                              hipStream_t stream) {
    char* ws = (char*)d_ws;
    float* h = (float*)(ws);                            // 25,600,000 B
    unsigned short* hb = (unsigned short*)(ws + 25600000);   // 12,800,000 B
    unsigned short* aggb = (unsigned short*)(ws + 38400000); // 12,800,000 B
    float* deg = (float*)(ws + 51200000);               // 400,000 B
    float* Wf = (float*)(ws + 51600000);                // 98,304 B
    float* bf = (float*)(ws + 51698304);                // 1,536 B
    int* rowptr = (int*)(ws + 51699840);                // 400,000 B
    int* csr = (int*)(ws + 52099840);                   // 4,800,000 B
    int* bsum = (int*)(ws + 56899840);                  // 512 B
    float* X = (float*)(ws + 56900352);                 // 2,097,152 B
    float* zbuf = (float*)(ws + 58997504);              // 16,384 B
    float* out = (float*)d_out;

    const float* emb_table = (const float*)d_in[7];
    const float* Wp = (const float*)d_in[8];
    const float* bp = (const float*)d_in[9];

    fusew_kernel<<<16, 256, 65536, stream>>>(
        (const float*)d_in[10], (const float*)d_in[12], (const float*)d_in[11],
        (const float*)d_in[16], (const float*)d_in[18], (const float*)d_in[17], Wf, bf);

    for (int g = 0; g < 2; ++g) {
        const int* adjg = (const int*)d_in[2 + g];
        // CSR build for this graph
        hipMemsetAsync(rowptr, 0, (size_t)NN * 4, stream);
        hist_kernel<<<(NE + 255) / 256, 256, 0, stream>>>(adjg, rowptr);
        scan1_kernel<<<SCAN_B, 256, 0, stream>>>(rowptr, bsum);
        scan2_kernel<<<1, 128, 0, stream>>>(bsum);
        scan3_kernel<<<SCAN_B, 256, 0, stream>>>(rowptr, bsum, deg);
        fill_kernel<<<(NE + 255) / 256, 256, 0, stream>>>(adjg, rowptr, csr);

        embed_kernel<<<NN / 4, 256, 0, stream>>>((const int*)d_in[g], emb_table, Wp, bp, h, hb);
        for (int l = 0; l < 2; ++l) {
            const float* Whh = (const float*)d_in[13 + 6 * l];
            const float* bih = (const float*)d_in[14 + 6 * l];
            const float* bhh = (const float*)d_in[15 + 6 * l];
            for (int ts = 0; ts < 3; ++ts) {
                agg_kernel<<<NN / 32, 256, 0, stream>>>(rowptr, csr, hb, aggb);
                gru_kernel<<<256, 512, 131072, stream>>>(h, hb, aggb, deg, Wf + l * 12288,
                                                         bf + l * 192, bih, Whh, bhh);
            }
        }
        gather_kernel<<<BT / 4, 256, 0, stream>>>((const int*)d_in[4 + g], h, X, g);
    }
    mlp_kernel<<<BT / 4, 256, 0, stream>>>(X, (const float*)d_in[22], (const float*)d_in[23],
                                           (const float*)d_in[24], (const float*)d_in[25], out, zbuf);
    loss_kernel<<<1, 256, 0, stream>>>(zbuf, (const int*)d_in[6], out);
}

// Round 4
// 1926.867 us; speedup vs baseline: 7.2554x; 1.1089x over previous
//
#include <hip/hip_runtime.h>
#include <math.h>

#define NN 100000
#define NE 1200000
#define EMBD 100
#define HD 64
#define BT 4096
#define SCAN_B 98  // 98 * 1024 >= NN

__device__ __forceinline__ float4 f4zero() { return make_float4(0.f, 0.f, 0.f, 0.f); }
__device__ __forceinline__ float4 f4fma(float4 acc, float4 w, float s) {
    acc.x = fmaf(w.x, s, acc.x);
    acc.y = fmaf(w.y, s, acc.y);
    acc.z = fmaf(w.z, s, acc.z);
    acc.w = fmaf(w.w, s, acc.w);
    return acc;
}
__device__ __forceinline__ float4 f4axpy(float4 b, float4 x, float s) { // b + s*x
    return make_float4(fmaf(s, x.x, b.x), fmaf(s, x.y, b.y), fmaf(s, x.z, b.z), fmaf(s, x.w, b.w));
}
__device__ __forceinline__ float sig1(float x) { return 1.f / (1.f + __expf(-x)); }
__device__ __forceinline__ float tanh1(float x) {
    x = fminf(fmaxf(x, -15.f), 15.f);
    float e = __expf(2.f * x);
    return (e - 1.f) / (e + 1.f);
}
// f32 -> bf16 (round-to-nearest-even), and bf16 -> f32 unpack helpers
__device__ __forceinline__ unsigned short f2b(float f) {
    unsigned u = __float_as_uint(f);
    u += 0x7fffu + ((u >> 16) & 1u);
    return (unsigned short)(u >> 16);
}
__device__ __forceinline__ float blo(unsigned u) { return __uint_as_float(u << 16); }
__device__ __forceinline__ float bhi(unsigned u) { return __uint_as_float(u & 0xffff0000u); }
__device__ __forceinline__ unsigned packb(float lo, float hi) {
    return (unsigned)f2b(lo) | ((unsigned)f2b(hi) << 16);
}

// ---- precompute Wf[l] = Wm[l] @ Wih[l] (64x192), bf[l] = bm[l] @ Wih[l] (192) ----
__global__ __launch_bounds__(256) void fusew_kernel(
    const float* __restrict__ Wm0, const float* __restrict__ Wih0, const float* __restrict__ bm0,
    const float* __restrict__ Wm1, const float* __restrict__ Wih1, const float* __restrict__ bm1,
    float* __restrict__ Wf, float* __restrict__ bf) {
    extern __shared__ float lds[];
    float* wm_s = lds;          // 4096
    float* wih_s = lds + 4096;  // 12288
    const int l = blockIdx.x >> 3, slice = blockIdx.x & 7;
    const float* Wm = l ? Wm1 : Wm0;
    const float* Wih = l ? Wih1 : Wih0;
    const float* bm = l ? bm1 : bm0;
    for (int i = threadIdx.x; i < 4096; i += 256) wm_s[i] = Wm[i];
    for (int i = threadIdx.x; i < 12288; i += 256) wih_s[i] = Wih[i];
    __syncthreads();
    float* Wfl = Wf + l * 12288;
    float* bfl = bf + l * 192;
    const int o0 = slice * 1536;
    for (int o = o0 + threadIdx.x; o < o0 + 1536; o += 256) {
        int r = o / 192, c = o % 192;
        float s = 0.f;
        for (int k = 0; k < 64; ++k) s = fmaf(wm_s[r * 64 + k], wih_s[k * 192 + c], s);
        Wfl[o] = s;
    }
    const int c0 = slice * 24;
    for (int c = c0 + threadIdx.x; c < c0 + 24; c += 256) {
        float s = 0.f;
        for (int k = 0; k < 64; ++k) s = fmaf(bm[k], wih_s[k * 192 + c], s);
        bfl[c] = s;
    }
}

// ---- h[n] = emb_table[ind[n]] @ Wp + bp ; also bf16 mirror hb ----
// Wave handles 4 nodes: rows cooperatively loaded (25 float4 each, all in flight),
// staged transposed in LDS, then k-loop = 1 coalesced Wp load + broadcast b128 + 4 FMA.
__global__ __launch_bounds__(256) void embed_kernel(
    const int* __restrict__ ind, const float* __restrict__ emb,
    const float* __restrict__ Wp, const float* __restrict__ bp,
    float* __restrict__ h, unsigned short* __restrict__ hb) {
    __shared__ float et[4][EMBD][4];  // [wave][k][node] = 6400 B
    const int w = threadIdx.x >> 6;
    const int l = threadIdx.x & 63;
    const int nodeBase = blockIdx.x * 16 + w * 4;
    // stage: f in {l, l+64} covers 100 float4 chunks (4 rows x 25 chunks)
    for (int f = l; f < 100; f += 64) {
        const int n = f / 25, c = f % 25;
        const int idx = ind[nodeBase + n];
        const float4 v = *(const float4*)(emb + (size_t)idx * EMBD + c * 4);
        et[w][c * 4 + 0][n] = v.x;
        et[w][c * 4 + 1][n] = v.y;
        et[w][c * 4 + 2][n] = v.z;
        et[w][c * 4 + 3][n] = v.w;
    }
    __syncthreads();
    float acc0 = bp[l], acc1 = acc0, acc2 = acc0, acc3 = acc0;
#pragma unroll 5
    for (int k = 0; k < EMBD; ++k) {
        const float wv = Wp[k * 64 + l];
        const float4 ev = *(const float4*)&et[w][k][0];  // wave-uniform -> broadcast
        acc0 = fmaf(ev.x, wv, acc0);
        acc1 = fmaf(ev.y, wv, acc1);
        acc2 = fmaf(ev.z, wv, acc2);
        acc3 = fmaf(ev.w, wv, acc3);
    }
    h[(nodeBase + 0) * 64 + l] = acc0;
    h[(nodeBase + 1) * 64 + l] = acc1;
    h[(nodeBase + 2) * 64 + l] = acc2;
    h[(nodeBase + 3) * 64 + l] = acc3;
    hb[(nodeBase + 0) * 64 + l] = f2b(acc0);
    hb[(nodeBase + 1) * 64 + l] = f2b(acc1);
    hb[(nodeBase + 2) * 64 + l] = f2b(acc2);
    hb[(nodeBase + 3) * 64 + l] = f2b(acc3);
}

// ---- CSR build: histogram of in-degree into rowptr (pre-zeroed) ----
__global__ __launch_bounds__(256) void hist_kernel(const int* __restrict__ adj, int* __restrict__ rowptr) {
    const int e = blockIdx.x * 256 + threadIdx.x;
    if (e < NE) atomicAdd(&rowptr[adj[2 * e + 1]], 1);
}

// ---- hierarchical exclusive scan over rowptr ----
__global__ __launch_bounds__(256) void scan1_kernel(const int* __restrict__ rowptr, int* __restrict__ bsum) {
    __shared__ int red[256];
    const int t = threadIdx.x, b = blockIdx.x;
    const int base = b * 1024;
    int s = 0;
    for (int i = t; i < 1024; i += 256) {
        const int idx = base + i;
        s += (idx < NN) ? rowptr[idx] : 0;
    }
    red[t] = s;
    __syncthreads();
    for (int off = 128; off > 0; off >>= 1) {
        if (t < off) red[t] += red[t + off];
        __syncthreads();
    }
    if (t == 0) bsum[b] = red[0];
}

__global__ __launch_bounds__(128) void scan2_kernel(int* __restrict__ bsum) {
    __shared__ int s[128];
    const int t = threadIdx.x;
    const int v = (t < SCAN_B) ? bsum[t] : 0;
    s[t] = v;
    __syncthreads();
    for (int off = 1; off < 128; off <<= 1) {
        const int x = (t >= off) ? s[t - off] : 0;
        __syncthreads();
        s[t] += x;
        __syncthreads();
    }
    if (t < SCAN_B) bsum[t] = s[t] - v;  // exclusive
}

__global__ __launch_bounds__(256) void scan3_kernel(int* __restrict__ rowptr, const int* __restrict__ bsum,
                                                    float* __restrict__ deg) {
    __shared__ int red[256];
    const int t = threadIdx.x, b = blockIdx.x;
    const int i0 = b * 1024 + t * 4;
    int v[4];
#pragma unroll
    for (int j = 0; j < 4; ++j) v[j] = (i0 + j < NN) ? rowptr[i0 + j] : 0;
    const int ts = v[0] + v[1] + v[2] + v[3];
    red[t] = ts;
    __syncthreads();
    for (int off = 1; off < 256; off <<= 1) {
        const int x = (t >= off) ? red[t - off] : 0;
        __syncthreads();
        red[t] += x;
        __syncthreads();
    }
    int pre = bsum[b] + red[t] - ts;  // exclusive prefix for this thread
#pragma unroll
    for (int j = 0; j < 4; ++j) {
        if (i0 + j < NN) {
            rowptr[i0 + j] = pre;
            deg[i0 + j] = (float)v[j];
            pre += v[j];
        }
    }
}

// ---- CSR build: fill. Uses rowptr as cursor; afterwards rowptr[n] == end offset of node n ----
__global__ __launch_bounds__(256) void fill_kernel(
    const int* __restrict__ adj, int* __restrict__ rowptr, int* __restrict__ csr) {
    const int e = blockIdx.x * 256 + threadIdx.x;
    if (e < NE) {
        const int2 st = ((const int2*)adj)[e];
        const int pos = atomicAdd(&rowptr[st.y], 1);
        csr[pos] = st.x;
    }
}

// ---- aggb[n] = bf16( sum over in-edges of hb[src] ). 8 lanes x 8 bf16 per node. ----
// rowptr is the SHIFTED array: range for node n is [ (n ? rowptr[n-1] : 0), rowptr[n] )
__global__ __launch_bounds__(256) void agg_kernel(
    const int* __restrict__ rowptr, const int* __restrict__ csr,
    const unsigned short* __restrict__ hb, unsigned short* __restrict__ aggb) {
    const int t = threadIdx.x;
    const int node = blockIdx.x * 32 + (t >> 3);
    const int c = t & 7;
    const int start = node ? rowptr[node - 1] : 0;
    const int end = rowptr[node];
    float acc[8];
#pragma unroll
    for (int j = 0; j < 8; ++j) acc[j] = 0.f;
    int e = start;
    for (; e + 3 < end; e += 4) {
        const int s0 = csr[e], s1 = csr[e + 1], s2 = csr[e + 2], s3 = csr[e + 3];
        const uint4 u0 = *(const uint4*)(hb + s0 * 64 + c * 8);
        const uint4 u1 = *(const uint4*)(hb + s1 * 64 + c * 8);
        const uint4 u2 = *(const uint4*)(hb + s2 * 64 + c * 8);
        const uint4 u3 = *(const uint4*)(hb + s3 * 64 + c * 8);
        acc[0] += blo(u0.x); acc[1] += bhi(u0.x); acc[2] += blo(u0.y); acc[3] += bhi(u0.y);
        acc[4] += blo(u0.z); acc[5] += bhi(u0.z); acc[6] += blo(u0.w); acc[7] += bhi(u0.w);
        acc[0] += blo(u1.x); acc[1] += bhi(u1.x); acc[2] += blo(u1.y); acc[3] += bhi(u1.y);
        acc[4] += blo(u1.z); acc[5] += bhi(u1.z); acc[6] += blo(u1.w); acc[7] += bhi(u1.w);
        acc[0] += blo(u2.x); acc[1] += bhi(u2.x); acc[2] += blo(u2.y); acc[3] += bhi(u2.y);
        acc[4] += blo(u2.z); acc[5] += bhi(u2.z); acc[6] += blo(u2.w); acc[7] += bhi(u2.w);
        acc[0] += blo(u3.x); acc[1] += bhi(u3.x); acc[2] += blo(u3.y); acc[3] += bhi(u3.y);
        acc[4] += blo(u3.z); acc[5] += bhi(u3.z); acc[6] += blo(u3.w); acc[7] += bhi(u3.w);
    }
    for (; e < end; ++e) {
        const int s0 = csr[e];
        const uint4 u0 = *(const uint4*)(hb + s0 * 64 + c * 8);
        acc[0] += blo(u0.x); acc[1] += bhi(u0.x); acc[2] += blo(u0.y); acc[3] += bhi(u0.y);
        acc[4] += blo(u0.z); acc[5] += bhi(u0.z); acc[6] += blo(u0.w); acc[7] += bhi(u0.w);
    }
    uint4 o;
    o.x = packb(acc[0], acc[1]);
    o.y = packb(acc[2], acc[3]);
    o.z = packb(acc[4], acc[5]);
    o.w = packb(acc[6], acc[7]);
    *(uint4*)(aggb + node * 64 + c * 8) = o;
}

// ---- fused GRU: gi = agg@Wf + deg*bf + bih ; gh = h@Whh + bhh ; elementwise -> h, hb
// 128-node tiles, 4 nodes/thread, a/h tiles bf16 k-major in LDS, weights fp32 in LDS.
__global__ __launch_bounds__(512, 1) void gru_kernel(
    float* __restrict__ h, unsigned short* __restrict__ hb,
    const unsigned short* __restrict__ aggb, const float* __restrict__ deg,
    const float* __restrict__ Wf, const float* __restrict__ bf,
    const float* __restrict__ bih, const float* __restrict__ Whh, const float* __restrict__ bhh) {
    extern __shared__ float lds[];
    float* wf_s = lds;                                      // 12288 f32
    float* wh_s = lds + 12288;                              // 12288 f32
    unsigned short* a_s = (unsigned short*)(lds + 24576);   // [64][128] bf16
    unsigned short* h_s = a_s + 8192;                       // [64][128] bf16
    const int t = threadIdx.x;
    const int cq = t & 15;        // col-quad within each 64-wide gate
    const int n0 = (t >> 4) * 4;  // first of this thread's 4 nodes within tile
    // stage weights once per block
    for (int i = t; i < 3072; i += 512) {
        ((float4*)wf_s)[i] = ((const float4*)Wf)[i];
        ((float4*)wh_s)[i] = ((const float4*)Whh)[i];
    }
    const float4 bihr = ((const float4*)bih)[cq], bihz = ((const float4*)bih)[16 + cq], bihg = ((const float4*)bih)[32 + cq];
    const float4 bfr = ((const float4*)bf)[cq], bfz = ((const float4*)bf)[16 + cq], bfg = ((const float4*)bf)[32 + cq];
    const float4 bhr = ((const float4*)bhh)[cq], bhz = ((const float4*)bhh)[16 + cq], bhg = ((const float4*)bhh)[32 + cq];
    // staging map: node sn (0..127), k-chunk skc*16
    const int sn = t >> 2, skc = (t & 3) * 16;
    const int ntiles = (NN + 127) >> 7;

    for (int tile = blockIdx.x; tile < ntiles; tile += gridDim.x) {
        const int base = tile << 7;
        __syncthreads();
        // ---- stage a_s, h_s (transpose to k-major) ----
        {
            const int node = base + sn;
            uint4 av0 = make_uint4(0, 0, 0, 0), av1 = make_uint4(0, 0, 0, 0);
            float4 hv0 = f4zero(), hv1 = f4zero(), hv2 = f4zero(), hv3 = f4zero();
            if (node < NN) {
                av0 = *(const uint4*)(aggb + node * 64 + skc);
                av1 = *(const uint4*)(aggb + node * 64 + skc + 8);
                const float4* hp = (const float4*)(h + node * 64 + skc);
                hv0 = hp[0]; hv1 = hp[1]; hv2 = hp[2]; hv3 = hp[3];
            }
            const unsigned au[4] = {av0.x, av0.y, av0.z, av0.w};
            const unsigned bu[4] = {av1.x, av1.y, av1.z, av1.w};
#pragma unroll
            for (int j = 0; j < 4; ++j) {
                a_s[(skc + 2 * j) * 128 + sn] = (unsigned short)(au[j] & 0xffffu);
                a_s[(skc + 2 * j + 1) * 128 + sn] = (unsigned short)(au[j] >> 16);
                a_s[(skc + 8 + 2 * j) * 128 + sn] = (unsigned short)(bu[j] & 0xffffu);
                a_s[(skc + 8 + 2 * j + 1) * 128 + sn] = (unsigned short)(bu[j] >> 16);
            }
            const float hf[16] = {hv0.x, hv0.y, hv0.z, hv0.w, hv1.x, hv1.y, hv1.z, hv1.w,
                                  hv2.x, hv2.y, hv2.z, hv2.w, hv3.x, hv3.y, hv3.z, hv3.w};
#pragma unroll
            for (int j = 0; j < 16; ++j) h_s[(skc + j) * 128 + sn] = f2b(hf[j]);
        }
        __syncthreads();
        // ---- init accumulators ----
        float d[4];
#pragma unroll
        for (int j = 0; j < 4; ++j) d[j] = (base + n0 + j < NN) ? deg[base + n0 + j] : 0.f;
        float4 gir[4], giz[4], gig[4], ghr[4], ghz[4], ghg[4];
#pragma unroll
        for (int j = 0; j < 4; ++j) {
            gir[j] = f4axpy(bihr, bfr, d[j]);
            giz[j] = f4axpy(bihz, bfz, d[j]);
            gig[j] = f4axpy(bihg, bfg, d[j]);
            ghr[j] = bhr; ghz[j] = bhz; ghg[j] = bhg;
        }
        // ---- K loop ----
#pragma unroll 2
        for (int k = 0; k < 64; ++k) {
            const float4 wfr = ((const float4*)(wf_s + k * 192))[cq];
            const float4 wfz = ((const float4*)(wf_s + k * 192 + 64))[cq];
            const float4 wfg = ((const float4*)(wf_s + k * 192 + 128))[cq];
            const float4 whr = ((const float4*)(wh_s + k * 192))[cq];
            const float4 whz = ((const float4*)(wh_s + k * 192 + 64))[cq];
            const float4 whg = ((const float4*)(wh_s + k * 192 + 128))[cq];
            const uint2 au = *(const uint2*)(a_s + k * 128 + n0);
            const uint2 hu = *(const uint2*)(h_s + k * 128 + n0);
            const float a[4] = {blo(au.x), bhi(au.x), blo(au.y), bhi(au.y)};
            const float hh[4] = {blo(hu.x), bhi(hu.x), blo(hu.y), bhi(hu.y)};
#pragma unroll
            for (int j = 0; j < 4; ++j) {
                gir[j] = f4fma(gir[j], wfr, a[j]);
                giz[j] = f4fma(giz[j], wfz, a[j]);
                gig[j] = f4fma(gig[j], wfg, a[j]);
                ghr[j] = f4fma(ghr[j], whr, hh[j]);
                ghz[j] = f4fma(ghz[j], whz, hh[j]);
                ghg[j] = f4fma(ghg[j], whg, hh[j]);
            }
        }
        // ---- epilogue ----
#pragma unroll
        for (int j = 0; j < 4; ++j) {
            const int node = base + n0 + j;
            if (node < NN) {
                const float4 hold = *(const float4*)(h + node * 64 + cq * 4);
                float4 r, z, ng, hn;
                r.x = sig1(gir[j].x + ghr[j].x); r.y = sig1(gir[j].y + ghr[j].y);
                r.z = sig1(gir[j].z + ghr[j].z); r.w = sig1(gir[j].w + ghr[j].w);
                z.x = sig1(giz[j].x + ghz[j].x); z.y = sig1(giz[j].y + ghz[j].y);
                z.z = sig1(giz[j].z + ghz[j].z); z.w = sig1(giz[j].w + ghz[j].w);
                ng.x = tanh1(fmaf(r.x, ghg[j].x, gig[j].x)); ng.y = tanh1(fmaf(r.y, ghg[j].y, gig[j].y));
                ng.z = tanh1(fmaf(r.z, ghg[j].z, gig[j].z)); ng.w = tanh1(fmaf(r.w, ghg[j].w, gig[j].w));
                hn.x = (1.f - z.x) * ng.x + z.x * hold.x; hn.y = (1.f - z.y) * ng.y + z.y * hold.y;
                hn.z = (1.f - z.z) * ng.z + z.z * hold.z; hn.w = (1.f - z.w) * ng.w + z.w * hold.w;
                *(float4*)(h + node * 64 + cq * 4) = hn;
                uint2 p;
                p.x = packb(hn.x, hn.y);
                p.y = packb(hn.z, hn.w);
                *(uint2*)(hb + node * 64 + cq * 4) = p;
            }
        }
    }
}

// ---- X[b, g*64 + j] = h[prop[b]][j] ----
__global__ __launch_bounds__(256) void gather_kernel(
    const int* __restrict__ prop, const float* __restrict__ h, float* __restrict__ X, int g) {
    const int b = blockIdx.x * 4 + (threadIdx.x >> 6);
    const int j = threadIdx.x & 63;
    X[b * 128 + g * 64 + j] = h[prop[b] * 64 + j];
}

// ---- hidden = relu(X@W1+b1); z = hidden@W2+b2; out[b]=sigmoid(z); zbuf[b]=z ----
__global__ __launch_bounds__(256) void mlp_kernel(
    const float* __restrict__ X, const float* __restrict__ W1, const float* __restrict__ b1,
    const float* __restrict__ W2, const float* __restrict__ b2,
    float* __restrict__ out, float* __restrict__ zbuf) {
    const int b = blockIdx.x * 4 + (threadIdx.x >> 6);
    const int j = threadIdx.x & 63;
    const float* x = X + b * 128;
    float acc = b1[j];
#pragma unroll 4
    for (int k = 0; k < 128; ++k) acc = fmaf(x[k], W1[k * 64 + j], acc);
    float v = fmaxf(acc, 0.f) * W2[j];
#pragma unroll
    for (int off = 32; off > 0; off >>= 1) v += __shfl_down(v, off);
    if (j == 0) {
        const float z = v + b2[0];
        out[b] = 1.f / (1.f + expf(-z));
        zbuf[b] = z;
    }
}

// ---- loss = -mean(y*logsig(z) + (1-y)*logsig(-z)) -> out[BT] ----
__global__ __launch_bounds__(256) void loss_kernel(
    const float* __restrict__ zbuf, const int* __restrict__ labels, float* __restrict__ out) {
    __shared__ float red[256];
    const int t = threadIdx.x;
    float s = 0.f;
    for (int i = t; i < BT; i += 256) {
        const float z = zbuf[i];
        const float y = (float)labels[i];
        const float lsp = (z >= 0.f) ? -log1pf(expf(-z)) : (z - log1pf(expf(z)));
        const float lsn = lsp - z;
        s += y * lsp + (1.f - y) * lsn;
    }
    red[t] = s;
    __syncthreads();
    for (int off = 128; off > 0; off >>= 1) {
        if (t < off) red[t] += red[t + off];
        __syncthreads();
    }
    if (t == 0) out[BT] = -red[0] / (float)BT;
}

extern "C" void kernel_launch(void* const* d_in, const int* in_sizes, int n_in,
                              void* d_out, int out_size, void* d_ws, size_t ws_size,
                              hipStream_t stream) {
    char* ws = (char*)d_ws;
    float* h = (float*)(ws);                            // 25,600,000 B
    unsigned short* hb = (unsigned short*)(ws + 25600000);   // 12,800,000 B
    unsigned short* aggb = (unsigned short*)(ws + 38400000); // 12,800,000 B
    float* deg = (float*)(ws + 51200000);               // 400,000 B
    float* Wf = (float*)(ws + 51600000);                // 98,304 B
    float* bf = (float*)(ws + 51698304);                // 1,536 B
    int* rowptr = (int*)(ws + 51699840);                // 400,000 B
    int* csr = (int*)(ws + 52099840);                   // 4,800,000 B
    int* bsum = (int*)(ws + 56899840);                  // 512 B
    float* X = (float*)(ws + 56900352);                 // 2,097,152 B
    float* zbuf = (float*)(ws + 58997504);              // 16,384 B
    float* out = (float*)d_out;

    const float* emb_table = (const float*)d_in[7];
    const float* Wp = (const float*)d_in[8];
    const float* bp = (const float*)d_in[9];

    fusew_kernel<<<16, 256, 65536, stream>>>(
        (const float*)d_in[10], (const float*)d_in[12], (const float*)d_in[11],
        (const float*)d_in[16], (const float*)d_in[18], (const float*)d_in[17], Wf, bf);

    for (int g = 0; g < 2; ++g) {
        const int* adjg = (const int*)d_in[2 + g];
        // CSR build for this graph
        hipMemsetAsync(rowptr, 0, (size_t)NN * 4, stream);
        hist_kernel<<<(NE + 255) / 256, 256, 0, stream>>>(adjg, rowptr);
        scan1_kernel<<<SCAN_B, 256, 0, stream>>>(rowptr, bsum);
        scan2_kernel<<<1, 128, 0, stream>>>(bsum);
        scan3_kernel<<<SCAN_B, 256, 0, stream>>>(rowptr, bsum, deg);
        fill_kernel<<<(NE + 255) / 256, 256, 0, stream>>>(adjg, rowptr, csr);

        embed_kernel<<<NN / 16, 256, 0, stream>>>((const int*)d_in[g], emb_table, Wp, bp, h, hb);
        for (int l = 0; l < 2; ++l) {
            const float* Whh = (const float*)d_in[13 + 6 * l];
            const float* bih = (const float*)d_in[14 + 6 * l];
            const float* bhh = (const float*)d_in[15 + 6 * l];
            for (int ts = 0; ts < 3; ++ts) {
                agg_kernel<<<NN / 32, 256, 0, stream>>>(rowptr, csr, hb, aggb);
                gru_kernel<<<256, 512, 131072, stream>>>(h, hb, aggb, deg, Wf + l * 12288,
                                                         bf + l * 192, bih, Whh, bhh);
            }
        }
        gather_kernel<<<BT / 4, 256, 0, stream>>>((const int*)d_in[4 + g], h, X, g);
    }
    mlp_kernel<<<BT / 4, 256, 0, stream>>>(X, (const float*)d_in[22], (const float*)d_in[23],
                                           (const float*)d_in[24], (const float*)d_in[25], out, zbuf);
    loss_kernel<<<1, 256, 0, stream>>>(zbuf, (const int*)d_in[6], out);
}

// Round 5
// 1630.014 us; speedup vs baseline: 8.5767x; 1.1821x over previous
//
#include <hip/hip_runtime.h>
#include <math.h>

#define NN 100000
#define NE 1200000
#define EMBD 100
#define HD 64
#define BT 4096
#define SCAN_B 98  // 98 * 1024 >= NN

typedef __attribute__((ext_vector_type(8))) short short8;  // 8 bf16 (4 VGPRs)
typedef __attribute__((ext_vector_type(4))) float f32x4;   // MFMA C/D

__device__ __forceinline__ float4 f4zero() { return make_float4(0.f, 0.f, 0.f, 0.f); }
__device__ __forceinline__ float sig1(float x) { return 1.f / (1.f + __expf(-x)); }
__device__ __forceinline__ float tanh1(float x) {
    x = fminf(fmaxf(x, -15.f), 15.f);
    float e = __expf(2.f * x);
    return (e - 1.f) / (e + 1.f);
}
// f32 -> bf16 (round-to-nearest-even), and bf16 -> f32 unpack helpers
__device__ __forceinline__ unsigned short f2b(float f) {
    unsigned u = __float_as_uint(f);
    u += 0x7fffu + ((u >> 16) & 1u);
    return (unsigned short)(u >> 16);
}
__device__ __forceinline__ float blo(unsigned u) { return __uint_as_float(u << 16); }
__device__ __forceinline__ float bhi(unsigned u) { return __uint_as_float(u & 0xffff0000u); }
__device__ __forceinline__ unsigned packb(float lo, float hi) {
    return (unsigned)f2b(lo) | ((unsigned)f2b(hi) << 16);
}

// ---- precompute Wf[l] = Wm[l] @ Wih[l] (64x192), bf[l] = bm[l] @ Wih[l] (192) ----
__global__ __launch_bounds__(256) void fusew_kernel(
    const float* __restrict__ Wm0, const float* __restrict__ Wih0, const float* __restrict__ bm0,
    const float* __restrict__ Wm1, const float* __restrict__ Wih1, const float* __restrict__ bm1,
    float* __restrict__ Wf, float* __restrict__ bf) {
    extern __shared__ float lds[];
    float* wm_s = lds;          // 4096
    float* wih_s = lds + 4096;  // 12288
    const int l = blockIdx.x >> 3, slice = blockIdx.x & 7;
    const float* Wm = l ? Wm1 : Wm0;
    const float* Wih = l ? Wih1 : Wih0;
    const float* bm = l ? bm1 : bm0;
    for (int i = threadIdx.x; i < 4096; i += 256) wm_s[i] = Wm[i];
    for (int i = threadIdx.x; i < 12288; i += 256) wih_s[i] = Wih[i];
    __syncthreads();
    float* Wfl = Wf + l * 12288;
    float* bfl = bf + l * 192;
    const int o0 = slice * 1536;
    for (int o = o0 + threadIdx.x; o < o0 + 1536; o += 256) {
        int r = o / 192, c = o % 192;
        float s = 0.f;
        for (int k = 0; k < 64; ++k) s = fmaf(wm_s[r * 64 + k], wih_s[k * 192 + c], s);
        Wfl[o] = s;
    }
    const int c0 = slice * 24;
    for (int c = c0 + threadIdx.x; c < c0 + 24; c += 256) {
        float s = 0.f;
        for (int k = 0; k < 64; ++k) s = fmaf(bm[k], wih_s[k * 192 + c], s);
        bfl[c] = s;
    }
}

// ---- pack W' (128x256) into MFMA B-fragment order, bf16 ----
// W' rows 0..63 = agg-k (Wf), rows 64..127 = h-k (Whh).
// cols: [0,64): r_sum = Wf_r / Whh_r ; [64,128): z_sum ; [128,192): ig = Wf_g / 0 ;
//       [192,256): hg = 0 / Whh_g.
// Fragment order: Wpk[l][frag = nt*4+kk][lane][j], element (k = kk*32+(lane>>4)*8+j,
// n = nt*16+(lane&15)).
__global__ __launch_bounds__(64) void wpack_kernel(
    const float* __restrict__ Wf, const float* __restrict__ Whh0, const float* __restrict__ Whh1,
    unsigned short* __restrict__ Wpk) {
    const int b = blockIdx.x;  // 0..127
    const int l = b >> 6, frag = b & 63;
    const int nt = frag >> 2, kk = frag & 3;
    const int lane = threadIdx.x;
    const int n = nt * 16 + (lane & 15);
    const int g = n >> 6, j = n & 63;
    const int k0 = kk * 32 + (lane >> 4) * 8;
    const float* wf = Wf + l * 12288;
    const float* whh = l ? Whh1 : Whh0;
    unsigned short o[8];
#pragma unroll
    for (int jj = 0; jj < 8; ++jj) {
        const int k = k0 + jj;
        float v = 0.f;
        if (k < 64) {
            if (g == 0) v = wf[k * 192 + j];
            else if (g == 1) v = wf[k * 192 + 64 + j];
            else if (g == 2) v = wf[k * 192 + 128 + j];
        } else {
            const int k2 = k - 64;
            if (g == 0) v = whh[k2 * 192 + j];
            else if (g == 1) v = whh[k2 * 192 + 64 + j];
            else if (g == 3) v = whh[k2 * 192 + 128 + j];
        }
        o[jj] = f2b(v);
    }
    *(uint4*)(Wpk + ((size_t)(l * 64 + frag) * 64 + lane) * 8) = *(const uint4*)o;
}

// ---- h[n] = emb_table[ind[n]] @ Wp + bp ; also bf16 mirror hb ----
__global__ __launch_bounds__(256) void embed_kernel(
    const int* __restrict__ ind, const float* __restrict__ emb,
    const float* __restrict__ Wp, const float* __restrict__ bp,
    float* __restrict__ h, unsigned short* __restrict__ hb) {
    __shared__ float et[4][EMBD][4];  // [wave][k][node]
    const int w = threadIdx.x >> 6;
    const int l = threadIdx.x & 63;
    const int nodeBase = blockIdx.x * 16 + w * 4;
    for (int f = l; f < 100; f += 64) {
        const int n = f / 25, c = f % 25;
        const int idx = ind[nodeBase + n];
        const float4 v = *(const float4*)(emb + (size_t)idx * EMBD + c * 4);
        et[w][c * 4 + 0][n] = v.x;
        et[w][c * 4 + 1][n] = v.y;
        et[w][c * 4 + 2][n] = v.z;
        et[w][c * 4 + 3][n] = v.w;
    }
    __syncthreads();
    float acc0 = bp[l], acc1 = acc0, acc2 = acc0, acc3 = acc0;
#pragma unroll 5
    for (int k = 0; k < EMBD; ++k) {
        const float wv = Wp[k * 64 + l];
        const float4 ev = *(const float4*)&et[w][k][0];
        acc0 = fmaf(ev.x, wv, acc0);
        acc1 = fmaf(ev.y, wv, acc1);
        acc2 = fmaf(ev.z, wv, acc2);
        acc3 = fmaf(ev.w, wv, acc3);
    }
    h[(nodeBase + 0) * 64 + l] = acc0;
    h[(nodeBase + 1) * 64 + l] = acc1;
    h[(nodeBase + 2) * 64 + l] = acc2;
    h[(nodeBase + 3) * 64 + l] = acc3;
    hb[(nodeBase + 0) * 64 + l] = f2b(acc0);
    hb[(nodeBase + 1) * 64 + l] = f2b(acc1);
    hb[(nodeBase + 2) * 64 + l] = f2b(acc2);
    hb[(nodeBase + 3) * 64 + l] = f2b(acc3);
}

// ---- CSR build: histogram of in-degree into rowptr (pre-zeroed) ----
__global__ __launch_bounds__(256) void hist_kernel(const int* __restrict__ adj, int* __restrict__ rowptr) {
    const int e = blockIdx.x * 256 + threadIdx.x;
    if (e < NE) atomicAdd(&rowptr[adj[2 * e + 1]], 1);
}

// ---- hierarchical exclusive scan over rowptr ----
__global__ __launch_bounds__(256) void scan1_kernel(const int* __restrict__ rowptr, int* __restrict__ bsum) {
    __shared__ int red[256];
    const int t = threadIdx.x, b = blockIdx.x;
    const int base = b * 1024;
    int s = 0;
    for (int i = t; i < 1024; i += 256) {
        const int idx = base + i;
        s += (idx < NN) ? rowptr[idx] : 0;
    }
    red[t] = s;
    __syncthreads();
    for (int off = 128; off > 0; off >>= 1) {
        if (t < off) red[t] += red[t + off];
        __syncthreads();
    }
    if (t == 0) bsum[b] = red[0];
}

__global__ __launch_bounds__(128) void scan2_kernel(int* __restrict__ bsum) {
    __shared__ int s[128];
    const int t = threadIdx.x;
    const int v = (t < SCAN_B) ? bsum[t] : 0;
    s[t] = v;
    __syncthreads();
    for (int off = 1; off < 128; off <<= 1) {
        const int x = (t >= off) ? s[t - off] : 0;
        __syncthreads();
        s[t] += x;
        __syncthreads();
    }
    if (t < SCAN_B) bsum[t] = s[t] - v;  // exclusive
}

__global__ __launch_bounds__(256) void scan3_kernel(int* __restrict__ rowptr, const int* __restrict__ bsum,
                                                    float* __restrict__ deg) {
    __shared__ int red[256];
    const int t = threadIdx.x, b = blockIdx.x;
    const int i0 = b * 1024 + t * 4;
    int v[4];
#pragma unroll
    for (int j = 0; j < 4; ++j) v[j] = (i0 + j < NN) ? rowptr[i0 + j] : 0;
    const int ts = v[0] + v[1] + v[2] + v[3];
    red[t] = ts;
    __syncthreads();
    for (int off = 1; off < 256; off <<= 1) {
        const int x = (t >= off) ? red[t - off] : 0;
        __syncthreads();
        red[t] += x;
        __syncthreads();
    }
    int pre = bsum[b] + red[t] - ts;
#pragma unroll
    for (int j = 0; j < 4; ++j) {
        if (i0 + j < NN) {
            rowptr[i0 + j] = pre;
            deg[i0 + j] = (float)v[j];
            pre += v[j];
        }
    }
}

// ---- CSR build: fill. Uses rowptr as cursor; afterwards rowptr[n] == end offset of node n ----
__global__ __launch_bounds__(256) void fill_kernel(
    const int* __restrict__ adj, int* __restrict__ rowptr, int* __restrict__ csr) {
    const int e = blockIdx.x * 256 + threadIdx.x;
    if (e < NE) {
        const int2 st = ((const int2*)adj)[e];
        const int pos = atomicAdd(&rowptr[st.y], 1);
        csr[pos] = st.x;
    }
}

// ---- aggb[n] = bf16( sum over in-edges of hb[src] ). 8 lanes x 8 bf16 per node. ----
__global__ __launch_bounds__(256) void agg_kernel(
    const int* __restrict__ rowptr, const int* __restrict__ csr,
    const unsigned short* __restrict__ hb, unsigned short* __restrict__ aggb) {
    const int t = threadIdx.x;
    const int node = blockIdx.x * 32 + (t >> 3);
    const int c = t & 7;
    const int start = node ? rowptr[node - 1] : 0;
    const int end = rowptr[node];
    float acc[8];
#pragma unroll
    for (int j = 0; j < 8; ++j) acc[j] = 0.f;
    int e = start;
    for (; e + 3 < end; e += 4) {
        const int s0 = csr[e], s1 = csr[e + 1], s2 = csr[e + 2], s3 = csr[e + 3];
        const uint4 u0 = *(const uint4*)(hb + s0 * 64 + c * 8);
        const uint4 u1 = *(const uint4*)(hb + s1 * 64 + c * 8);
        const uint4 u2 = *(const uint4*)(hb + s2 * 64 + c * 8);
        const uint4 u3 = *(const uint4*)(hb + s3 * 64 + c * 8);
        acc[0] += blo(u0.x); acc[1] += bhi(u0.x); acc[2] += blo(u0.y); acc[3] += bhi(u0.y);
        acc[4] += blo(u0.z); acc[5] += bhi(u0.z); acc[6] += blo(u0.w); acc[7] += bhi(u0.w);
        acc[0] += blo(u1.x); acc[1] += bhi(u1.x); acc[2] += blo(u1.y); acc[3] += bhi(u1.y);
        acc[4] += blo(u1.z); acc[5] += bhi(u1.z); acc[6] += blo(u1.w); acc[7] += bhi(u1.w);
        acc[0] += blo(u2.x); acc[1] += bhi(u2.x); acc[2] += blo(u2.y); acc[3] += bhi(u2.y);
        acc[4] += blo(u2.z); acc[5] += bhi(u2.z); acc[6] += blo(u2.w); acc[7] += bhi(u2.w);
        acc[0] += blo(u3.x); acc[1] += bhi(u3.x); acc[2] += blo(u3.y); acc[3] += bhi(u3.y);
        acc[4] += blo(u3.z); acc[5] += bhi(u3.z); acc[6] += blo(u3.w); acc[7] += bhi(u3.w);
    }
    for (; e < end; ++e) {
        const int s0 = csr[e];
        const uint4 u0 = *(const uint4*)(hb + s0 * 64 + c * 8);
        acc[0] += blo(u0.x); acc[1] += bhi(u0.x); acc[2] += blo(u0.y); acc[3] += bhi(u0.y);
        acc[4] += blo(u0.z); acc[5] += bhi(u0.z); acc[6] += blo(u0.w); acc[7] += bhi(u0.w);
    }
    uint4 o;
    o.x = packb(acc[0], acc[1]);
    o.y = packb(acc[2], acc[3]);
    o.z = packb(acc[4], acc[5]);
    o.w = packb(acc[6], acc[7]);
    *(uint4*)(aggb + node * 64 + c * 8) = o;
}

// ---- MFMA GRU: per 16-node tile, [agg|h] (16x128) @ W' (128x256) -> r,z,ig,hg; gates; h,hb.
// Wave handles 32 nodes (2 M-tiles). Weights in LDS (64 KB, fragment order).
// A frags loaded straight from global (A[m=lane&15][k=quad*8+j] = 16 contiguous bytes).
__global__ __launch_bounds__(256) void gru_mfma_kernel(
    float* __restrict__ h, unsigned short* __restrict__ hb,
    const unsigned short* __restrict__ aggb, const float* __restrict__ deg,
    const unsigned short* __restrict__ Wpk, const float* __restrict__ bf,
    const float* __restrict__ bih, const float* __restrict__ bhh) {
    extern __shared__ unsigned short ldsW[];  // 64 frags x 64 lanes x 8 bf16 = 64 KB
    {
        const uint4* src = (const uint4*)Wpk;
        uint4* dst = (uint4*)ldsW;
        for (int i = threadIdx.x; i < 4096; i += 256) dst[i] = src[i];
    }
    __syncthreads();
    const int lane = threadIdx.x & 63;
    const int j0 = lane & 15, quad = lane >> 4;
    const int q8 = quad * 8;
    // bias preload (col = c4*16 + j0 within each 64-wide gate)
    float cr[4], cz[4], cig[4], chg[4], vbfr[4], vbfz[4], vbfg[4];
#pragma unroll
    for (int c4 = 0; c4 < 4; ++c4) {
        const int col = c4 * 16 + j0;
        cr[c4] = bih[col] + bhh[col];
        cz[c4] = bih[64 + col] + bhh[64 + col];
        cig[c4] = bih[128 + col];
        chg[c4] = bhh[128 + col];
        vbfr[c4] = bf[col];
        vbfz[c4] = bf[64 + col];
        vbfg[c4] = bf[128 + col];
    }
    const short8* ldsW8 = (const short8*)ldsW;
    const int gw = blockIdx.x * 4 + (threadIdx.x >> 6);
    const int nw = gridDim.x * 4;

    auto epilogue = [&](const f32x4(&acc)[16], int nb) {
#pragma unroll
        for (int reg = 0; reg < 4; ++reg) {
            const int node = nb + reg;
            const float dg = deg[node];
#pragma unroll
            for (int c4 = 0; c4 < 4; ++c4) {
                const int col = c4 * 16 + j0;
                const float rv = sig1(acc[c4][reg] + cr[c4] + dg * vbfr[c4]);
                const float zv = sig1(acc[4 + c4][reg] + cz[c4] + dg * vbfz[c4]);
                const float gi = acc[8 + c4][reg] + cig[c4] + dg * vbfg[c4];
                const float gh = acc[12 + c4][reg] + chg[c4];
                const float nv = tanh1(fmaf(rv, gh, gi));
                const float hold = h[node * 64 + col];
                const float hn = (1.f - zv) * nv + zv * hold;
                h[node * 64 + col] = hn;
                hb[node * 64 + col] = f2b(hn);
            }
        }
    };

    for (int t = gw; t < NN / 32; t += nw) {
        const int mbase = t * 32;
        const int node0 = mbase + j0, node1 = node0 + 16;
        short8 a[4], b[4];
        a[0] = *(const short8*)(aggb + node0 * 64 + q8);
        a[1] = *(const short8*)(aggb + node0 * 64 + 32 + q8);
        a[2] = *(const short8*)(hb + node0 * 64 + q8);
        a[3] = *(const short8*)(hb + node0 * 64 + 32 + q8);
        b[0] = *(const short8*)(aggb + node1 * 64 + q8);
        b[1] = *(const short8*)(aggb + node1 * 64 + 32 + q8);
        b[2] = *(const short8*)(hb + node1 * 64 + q8);
        b[3] = *(const short8*)(hb + node1 * 64 + 32 + q8);
        f32x4 acc0[16], acc1[16];
#pragma unroll
        for (int i = 0; i < 16; ++i) {
            acc0[i] = (f32x4){0.f, 0.f, 0.f, 0.f};
            acc1[i] = (f32x4){0.f, 0.f, 0.f, 0.f};
        }
#pragma unroll
        for (int nt = 0; nt < 16; ++nt) {
#pragma unroll
            for (int kk = 0; kk < 4; ++kk) {
                const short8 w = ldsW8[(nt * 4 + kk) * 64 + lane];
                acc0[nt] = __builtin_amdgcn_mfma_f32_16x16x32_bf16(a[kk], w, acc0[nt], 0, 0, 0);
                acc1[nt] = __builtin_amdgcn_mfma_f32_16x16x32_bf16(b[kk], w, acc1[nt], 0, 0, 0);
            }
        }
        epilogue(acc0, mbase + quad * 4);
        epilogue(acc1, mbase + 16 + quad * 4);
    }
}

// ---- X[b, g*64 + j] = h[prop[b]][j] ----
__global__ __launch_bounds__(256) void gather_kernel(
    const int* __restrict__ prop, const float* __restrict__ h, float* __restrict__ X, int g) {
    const int b = blockIdx.x * 4 + (threadIdx.x >> 6);
    const int j = threadIdx.x & 63;
    X[b * 128 + g * 64 + j] = h[prop[b] * 64 + j];
}

// ---- hidden = relu(X@W1+b1); z = hidden@W2+b2; out[b]=sigmoid(z); zbuf[b]=z ----
__global__ __launch_bounds__(256) void mlp_kernel(
    const float* __restrict__ X, const float* __restrict__ W1, const float* __restrict__ b1,
    const float* __restrict__ W2, const float* __restrict__ b2,
    float* __restrict__ out, float* __restrict__ zbuf) {
    const int b = blockIdx.x * 4 + (threadIdx.x >> 6);
    const int j = threadIdx.x & 63;
    const float* x = X + b * 128;
    float acc = b1[j];
#pragma unroll 4
    for (int k = 0; k < 128; ++k) acc = fmaf(x[k], W1[k * 64 + j], acc);
    float v = fmaxf(acc, 0.f) * W2[j];
#pragma unroll
    for (int off = 32; off > 0; off >>= 1) v += __shfl_down(v, off);
    if (j == 0) {
        const float z = v + b2[0];
        out[b] = 1.f / (1.f + expf(-z));
        zbuf[b] = z;
    }
}

// ---- loss = -mean(y*logsig(z) + (1-y)*logsig(-z)) -> out[BT] ----
__global__ __launch_bounds__(256) void loss_kernel(
    const float* __restrict__ zbuf, const int* __restrict__ labels, float* __restrict__ out) {
    __shared__ float red[256];
    const int t = threadIdx.x;
    float s = 0.f;
    for (int i = t; i < BT; i += 256) {
        const float z = zbuf[i];
        const float y = (float)labels[i];
        const float lsp = (z >= 0.f) ? -log1pf(expf(-z)) : (z - log1pf(expf(z)));
        const float lsn = lsp - z;
        s += y * lsp + (1.f - y) * lsn;
    }
    red[t] = s;
    __syncthreads();
    for (int off = 128; off > 0; off >>= 1) {
        if (t < off) red[t] += red[t + off];
        __syncthreads();
    }
    if (t == 0) out[BT] = -red[0] / (float)BT;
}

extern "C" void kernel_launch(void* const* d_in, const int* in_sizes, int n_in,
                              void* d_out, int out_size, void* d_ws, size_t ws_size,
                              hipStream_t stream) {
    char* ws = (char*)d_ws;
    float* h = (float*)(ws);                                  // 25,600,000 B
    unsigned short* hb = (unsigned short*)(ws + 25600000);    // 12,800,000 B
    unsigned short* aggb = (unsigned short*)(ws + 38400000);  // 12,800,000 B
    float* deg = (float*)(ws + 51200000);                     // 400,000 B
    float* Wf = (float*)(ws + 51600000);                      // 98,304 B
    float* bf = (float*)(ws + 51698304);                      // 1,536 B
    int* rowptr = (int*)(ws + 51699840);                      // 400,000 B
    int* csr = (int*)(ws + 52099840);                         // 4,800,000 B
    int* bsum = (int*)(ws + 56899840);                        // 512 B
    float* X = (float*)(ws + 56900352);                       // 2,097,152 B
    float* zbuf = (float*)(ws + 58997504);                    // 16,384 B
    unsigned short* Wpk = (unsigned short*)(ws + 59013888);   // 131,072 B
    float* out = (float*)d_out;

    const float* emb_table = (const float*)d_in[7];
    const float* Wp = (const float*)d_in[8];
    const float* bp = (const float*)d_in[9];

    fusew_kernel<<<16, 256, 65536, stream>>>(
        (const float*)d_in[10], (const float*)d_in[12], (const float*)d_in[11],
        (const float*)d_in[16], (const float*)d_in[18], (const float*)d_in[17], Wf, bf);
    wpack_kernel<<<128, 64, 0, stream>>>(Wf, (const float*)d_in[13], (const float*)d_in[19], Wpk);

    for (int g = 0; g < 2; ++g) {
        const int* adjg = (const int*)d_in[2 + g];
        // CSR build for this graph
        hipMemsetAsync(rowptr, 0, (size_t)NN * 4, stream);
        hist_kernel<<<(NE + 255) / 256, 256, 0, stream>>>(adjg, rowptr);
        scan1_kernel<<<SCAN_B, 256, 0, stream>>>(rowptr, bsum);
        scan2_kernel<<<1, 128, 0, stream>>>(bsum);
        scan3_kernel<<<SCAN_B, 256, 0, stream>>>(rowptr, bsum, deg);
        fill_kernel<<<(NE + 255) / 256, 256, 0, stream>>>(adjg, rowptr, csr);

        embed_kernel<<<NN / 16, 256, 0, stream>>>((const int*)d_in[g], emb_table, Wp, bp, h, hb);
        for (int l = 0; l < 2; ++l) {
            const float* bih = (const float*)d_in[14 + 6 * l];
            const float* bhh = (const float*)d_in[15 + 6 * l];
            for (int ts = 0; ts < 3; ++ts) {
                agg_kernel<<<NN / 32, 256, 0, stream>>>(rowptr, csr, hb, aggb);
                gru_mfma_kernel<<<512, 256, 65536, stream>>>(h, hb, aggb, deg, Wpk + l * 32768,
                                                             bf + l * 192, bih, bhh);
            }
        }
        gather_kernel<<<BT / 4, 256, 0, stream>>>((const int*)d_in[4 + g], h, X, g);
    }
    mlp_kernel<<<BT / 4, 256, 0, stream>>>(X, (const float*)d_in[22], (const float*)d_in[23],
                                           (const float*)d_in[24], (const float*)d_in[25], out, zbuf);
    loss_kernel<<<1, 256, 0, stream>>>(zbuf, (const int*)d_in[6], out);
}